// Round 17
// baseline (361.689 us; speedup 1.0000x reference)
//
#include <hip/hip_runtime.h>
#include <hip/hip_bf16.h>
#include <math.h>

#define BATCH  2
#define SEQ    2048
#define HID    1024
#define INNER  2048
#define NSTATE 64
#define NTOK   (BATCH * SEQ)
#define TCHUNK 64
#define NCHUNK (SEQ / TCHUNK)
#define NMID   (INNER + 2 * NSTATE)   // 2176
#define LDH    1056
#define LDI    2080

typedef __bf16 bf16x8 __attribute__((ext_vector_type(8)));
typedef float  f32x4  __attribute__((ext_vector_type(4)));

typedef const __attribute__((address_space(1))) char* gas_ptr;
typedef __attribute__((address_space(3))) char*       las_ptr;

__device__ __forceinline__ void gload16(const void* g, void* l) {
  __builtin_amdgcn_global_load_lds((gas_ptr)g, (las_ptr)l, 16, 0, 0);
}

__device__ __forceinline__ unsigned short f2bf(float f) {
  __hip_bfloat16 h = __float2bfloat16(f);
  return __builtin_bit_cast(unsigned short, h);
}
__device__ __forceinline__ float bf2f(unsigned short u) {
  unsigned int x = ((unsigned int)u) << 16;
  return __builtin_bit_cast(float, x);
}

// ---------------------------------------------------------------- cvt fp32->bf16 (padded rows)
__global__ __launch_bounds__(256) void cvt_pad_kernel(
    const float* __restrict__ in, __hip_bfloat16* __restrict__ out, int n4) {
  int i = blockIdx.x * 256 + threadIdx.x;
  if (i >= n4) return;
  const int r = i >> 8;
  const int c = (i & 255) * 4;
  float4 v = *(const float4*)&in[(size_t)r * HID + c];
  ushort4 u;
  u.x = f2bf(v.x); u.y = f2bf(v.y); u.z = f2bf(v.z); u.w = f2bf(v.w);
  *(ushort4*)&out[(size_t)r * LDH + c] = u;
}

// ------------------------------------------------- transpose fp32 [R][C] -> bf16 [C][ostride]
__global__ __launch_bounds__(256) void transpose_cvt_kernel(
    const float* __restrict__ in, __hip_bfloat16* __restrict__ out,
    int R, int C, int ostride) {
  __shared__ float tile[32][33];
  int tx = threadIdx.x & 31, ty = threadIdx.x >> 5;
  int c0 = blockIdx.x * 32, r0 = blockIdx.y * 32;
#pragma unroll
  for (int i = 0; i < 4; ++i)
    tile[ty + 8 * i][tx] = in[(size_t)(r0 + ty + 8 * i) * C + c0 + tx];
  __syncthreads();
#pragma unroll
  for (int i = 0; i < 4; ++i)
    out[(size_t)(c0 + ty + 8 * i) * ostride + r0 + tx] =
        __float2bfloat16(tile[tx][ty + 8 * i]);
}

// ---------------------------------------------------------------- GEMM (r12-proven: 128x128, BK=64)
// EPI 0: fp32 Cout. EPI 1: bf16 split xin|z. EPI 2: bf16 split-K partial to o0 (stride ldc).
template <int EPI>
__global__ __launch_bounds__(256, 4) void gemm_bt_kernel(
    const __hip_bfloat16* __restrict__ A, const __hip_bfloat16* __restrict__ Bt,
    int M, int N, int Klen, int ldk, int gridN, int nwg, int mnwg,
    float* __restrict__ Cout, int ldc, int ldo,
    __hip_bfloat16* __restrict__ o0, __hip_bfloat16* __restrict__ o1) {
  __shared__ __align__(16) __hip_bfloat16 As[128 * 64];
  __shared__ __align__(16) __hip_bfloat16 Bs[128 * 64];
  const int tid = threadIdx.x;
  const int lane = tid & 63;
  const int w = tid >> 6;
  const int wr = w >> 1, wc = w & 1;

  const int orig = blockIdx.x;
  const int q8 = nwg >> 3, r8 = nwg & 7;
  const int xcd = orig & 7, seq = orig >> 3;
  const int wg = (xcd < r8 ? xcd * (q8 + 1) : r8 * (q8 + 1) + (xcd - r8) * q8) + seq;
  const int kz = wg / mnwg;
  const int wgr = wg - kz * mnwg;
  const int m0 = (wgr / gridN) * 128;
  const int n0 = (wgr % gridN) * 128;

  const __hip_bfloat16* Ab = A + (size_t)kz * Klen;
  const __hip_bfloat16* Bb = Bt + (size_t)kz * Klen;

  f32x4 acc[4][4];
#pragma unroll
  for (int i = 0; i < 4; ++i)
#pragma unroll
    for (int j = 0; j < 4; ++j)
#pragma unroll
      for (int r2 = 0; r2 < 4; ++r2) acc[i][j][r2] = 0.f;

  const int g8row = lane >> 3;
  const int scol = ((lane & 7) ^ g8row) * 8;
  const __hip_bfloat16* Agp = Ab + (size_t)(m0 + w * 32 + g8row) * ldk + scol;
  const __hip_bfloat16* Bgp = Bb + (size_t)(n0 + w * 32 + g8row) * ldk + scol;
  __hip_bfloat16* lA = As + (w * 32) * 64;
  __hip_bfloat16* lB = Bs + (w * 32) * 64;

  const int lrow = lane & 15, lk = lane >> 4;
  const int arow0 = wr * 64 + lrow;
  const int brow0 = wc * 64 + lrow;

  const int nt = Klen >> 6;
  for (int t = 0; t < nt; ++t) {
    __syncthreads();
#pragma unroll
    for (int g = 0; g < 4; ++g) {
      gload16(Agp + (size_t)(g * 8) * ldk + t * 64, lA + (g * 8) * 64);
      gload16(Bgp + (size_t)(g * 8) * ldk + t * 64, lB + (g * 8) * 64);
    }
    __syncthreads();
#pragma unroll
    for (int ss = 0; ss < 2; ++ss) {
      bf16x8 af[4], bv[4];
#pragma unroll
      for (int i = 0; i < 4; ++i) {
        const int ra = arow0 + i * 16;
        af[i] = *(const bf16x8*)(As + ra * 64 + (((ss * 4 + lk) ^ (ra & 7)) * 8));
        const int rb = brow0 + i * 16;
        bv[i] = *(const bf16x8*)(Bs + rb * 64 + (((ss * 4 + lk) ^ (rb & 7)) * 8));
      }
#pragma unroll
      for (int i = 0; i < 4; ++i)
#pragma unroll
        for (int j = 0; j < 4; ++j)
          acc[i][j] = __builtin_amdgcn_mfma_f32_16x16x32_bf16(af[i], bv[j], acc[i][j], 0, 0, 0);
    }
  }

#pragma unroll
  for (int i = 0; i < 4; ++i) {
#pragma unroll
    for (int j = 0; j < 4; ++j) {
#pragma unroll
      for (int r2 = 0; r2 < 4; ++r2) {
        const int row = m0 + wr * 64 + i * 16 + lk * 4 + r2;
        const int col = n0 + wc * 64 + j * 16 + lrow;
        const float v = acc[i][j][r2];
        if constexpr (EPI == 0) {
          Cout[(size_t)kz * M * ldc + (size_t)row * ldc + col] = v;
        } else if constexpr (EPI == 1) {
          if (col < INNER) o0[(size_t)row * ldo + col] = __float2bfloat16(v);
          else             o1[(size_t)row * ldo + (col - INNER)] = __float2bfloat16(v);
        } else {
          o0[(size_t)kz * M * ldc + (size_t)row * ldc + col] = __float2bfloat16(v);
        }
      }
    }
  }
}

// ---------------------------------------------------------------- split-K4 reduce (bf16 partials -> fp32 out)
__global__ __launch_bounds__(256) void reduce4b_kernel(
    const __hip_bfloat16* __restrict__ P, float* __restrict__ out, int n4) {
  int i = blockIdx.x * 256 + threadIdx.x;
  if (i >= n4) return;
  float4 acc = make_float4(0.f, 0.f, 0.f, 0.f);
#pragma unroll
  for (int pp = 0; pp < 4; ++pp) {
    ushort4 u = ((const ushort4*)P)[(size_t)pp * n4 + i];
    acc.x += bf2f(u.x); acc.y += bf2f(u.y); acc.z += bf2f(u.z); acc.w += bf2f(u.w);
  }
  ((float4*)out)[i] = acc;
}

// ---------------------------------------------------------------- causal depthwise conv + silu
__global__ __launch_bounds__(256) void conv_silu_kernel(
    const __hip_bfloat16* __restrict__ xin, const float* __restrict__ cw,
    const float* __restrict__ cb, __hip_bfloat16* __restrict__ xch) {
  int idx = blockIdx.x * 256 + threadIdx.x;
  int cg = idx & 511;
  int tok = idx >> 9;
  int c = cg * 4;
  int l = tok & (SEQ - 1);
  float wv[4][4];
#pragma unroll
  for (int i = 0; i < 4; ++i) {
    float4 w = *(const float4*)&cw[(c + i) * 4];
    wv[i][0] = w.x; wv[i][1] = w.y; wv[i][2] = w.z; wv[i][3] = w.w;
  }
  float4 bias = *(const float4*)&cb[c];
  float r0 = bias.x, r1 = bias.y, r2 = bias.z, r3 = bias.w;
#pragma unroll
  for (int k = 0; k < 4; ++k) {
    const int d = 3 - k;
    if (l >= d) {
      ushort4 xv = *(const ushort4*)&xin[(size_t)(tok - d) * LDI + c];
      r0 = fmaf(bf2f(xv.x), wv[0][k], r0);
      r1 = fmaf(bf2f(xv.y), wv[1][k], r1);
      r2 = fmaf(bf2f(xv.z), wv[2][k], r2);
      r3 = fmaf(bf2f(xv.w), wv[3][k], r3);
    }
  }
  r0 = r0 / (1.f + __expf(-r0));
  r1 = r1 / (1.f + __expf(-r1));
  r2 = r2 / (1.f + __expf(-r2));
  r3 = r3 / (1.f + __expf(-r3));
  ushort4 u;
  u.x = f2bf(r0); u.y = f2bf(r1); u.z = f2bf(r2); u.w = f2bf(r3);
  *(ushort4*)&xch[(size_t)tok * LDI + c] = u;
}

// ---------------------------------------------------------------- cumv: P0+P1 -> softplus(dt) -> cumA(bf16) + wT
// Absorbs the former reduce_mid INNER path; dtx eliminated. 8-deep double-buffered loads.
__global__ __launch_bounds__(256) void cumv_kernel(
    const __hip_bfloat16* __restrict__ P, const float* __restrict__ bdt,
    const __hip_bfloat16* __restrict__ xch,
    unsigned short* __restrict__ cumA, unsigned int* __restrict__ wT) {
  const int bk = blockIdx.y;
  const int c = blockIdx.x * 256 + threadIdx.x;
  const int b = bk >> 5, k = bk & 31;
  const size_t tokbase = (size_t)(b * SEQ + k * TCHUNK);
  const float bb = bdt[c];
  const unsigned short* P0 = (const unsigned short*)P;
  const unsigned short* P1 = (const unsigned short*)P + (size_t)NTOK * NMID;
  const unsigned short* XC = (const unsigned short*)xch;

  float p0a[8], p1a[8], xca[8], p0b[8], p1b[8], xcb[8];
#define LOADB(tb, A0, A1, A2)                              \
  do {                                                     \
    _Pragma("unroll")                                      \
    for (int j = 0; j < 8; ++j) {                          \
      const size_t row = tokbase + (tb) + j;               \
      A0[j] = bf2f(P0[row * NMID + c]);                    \
      A1[j] = bf2f(P1[row * NMID + c]);                    \
      A2[j] = bf2f(XC[row * LDI + c]);                     \
    }                                                      \
  } while (0)

  float cum = 1.f;
  unsigned int wreg[32];
  LOADB(0, p0a, p1a, xca);
#pragma unroll
  for (int tb = 0; tb < 64; tb += 16) {
    LOADB(tb + 8, p0b, p1b, xcb);
#pragma unroll
    for (int j = 0; j < 8; ++j) {
      const int t = tb + j;
      const float dpre = p0a[j] + p1a[j] + bb;
      const float dtv = (dpre > 15.f) ? dpre : log1pf(__expf(dpre));
      cum *= __expf(-dtv);
      cum = fmaxf(cum, 1e-30f);
      cumA[(tokbase + t) * INNER + c] = f2bf(cum);
      const unsigned short wb = f2bf(dtv * xca[j] / cum);
      if (t & 1) wreg[t >> 1] |= ((unsigned int)wb) << 16;
      else       wreg[t >> 1] = (unsigned int)wb;
    }
    if (tb + 16 < 64) LOADB(tb + 16, p0a, p1a, xca);
#pragma unroll
    for (int j = 0; j < 8; ++j) {
      const int t = tb + 8 + j;
      const float dpre = p0b[j] + p1b[j] + bb;
      const float dtv = (dpre > 15.f) ? dpre : log1pf(__expf(dpre));
      cum *= __expf(-dtv);
      cum = fmaxf(cum, 1e-30f);
      cumA[(tokbase + t) * INNER + c] = f2bf(cum);
      const unsigned short wb = f2bf(dtv * xcb[j] / cum);
      if (t & 1) wreg[t >> 1] |= ((unsigned int)wb) << 16;
      else       wreg[t >> 1] = (unsigned int)wb;
    }
  }
#undef LOADB
  uint4* dst = (uint4*)(wT + ((size_t)bk * INNER + c) * 32);
#pragma unroll
  for (int j = 0; j < 8; ++j)
    dst[j] = make_uint4(wreg[4 * j], wreg[4 * j + 1], wreg[4 * j + 2], wreg[4 * j + 3]);
}

// ---------------------------------------------------------------- chunkG: P(B|C cols) -> tril(C@B^T), C/B^T copies
// 4 blocks per chunk (t-quartered). Absorbs the former reduce_mid B/C path.
__global__ __launch_bounds__(256) void chunkG_kernel(
    const __hip_bfloat16* __restrict__ P,
    __hip_bfloat16* __restrict__ Abuf, __hip_bfloat16* __restrict__ BtBuf) {
  __shared__ float Bsh[TCHUNK][NSTATE + 4];
  __shared__ float Csh[16][NSTATE + 4];
  const int blk = blockIdx.x;
  const int bk = blk >> 2, qt = blk & 3;
  const int b = bk >> 5, k = bk & 31;
  const int tid = threadIdx.x;
  const size_t tokbase = (size_t)(b * SEQ + k * TCHUNK);
  const unsigned short* P0 = (const unsigned short*)P;
  const unsigned short* P1 = (const unsigned short*)P + (size_t)NTOK * NMID;

  for (int i = tid; i < TCHUNK * 16; i += 256) {
    const int row = i >> 4, q = i & 15;
    const size_t off = (tokbase + row) * NMID + INNER + q * 4;
    ushort4 u0 = *(const ushort4*)&P0[off];
    ushort4 u1 = *(const ushort4*)&P1[off];
    *(float4*)&Bsh[row][q * 4] = make_float4(
        bf2f(u0.x) + bf2f(u1.x), bf2f(u0.y) + bf2f(u1.y),
        bf2f(u0.z) + bf2f(u1.z), bf2f(u0.w) + bf2f(u1.w));
  }
  for (int i = tid; i < 16 * 16; i += 256) {
    const int row = i >> 4, q = i & 15;
    const size_t off = (tokbase + qt * 16 + row) * NMID + INNER + NSTATE + q * 4;
    ushort4 u0 = *(const ushort4*)&P0[off];
    ushort4 u1 = *(const ushort4*)&P1[off];
    *(float4*)&Csh[row][q * 4] = make_float4(
        bf2f(u0.x) + bf2f(u1.x), bf2f(u0.y) + bf2f(u1.y),
        bf2f(u0.z) + bf2f(u1.z), bf2f(u0.w) + bf2f(u1.w));
  }
  __syncthreads();
  for (int e = tid; e < 16 * 64; e += 256) {
    const int tl = e >> 6, tau = e & 63;
    const int t = qt * 16 + tl;
    float g = 0.f;
    if (tau <= t) {
#pragma unroll
      for (int q = 0; q < 16; ++q) {
        const float4 cv = *(const float4*)&Csh[tl][q * 4];
        const float4 bv = *(const float4*)&Bsh[tau][q * 4];
        g += cv.x * bv.x + cv.y * bv.y + cv.z * bv.z + cv.w * bv.w;
      }
    }
    Abuf[((size_t)bk * 64 + t) * 128 + tau] = __float2bfloat16(g);
  }
  for (int e = tid; e < 16 * 64; e += 256) {
    const int n2l = e >> 6, r = e & 63;
    const int n2 = qt * 16 + n2l;
    BtBuf[((size_t)bk * 64 + n2) * 64 + r] = __float2bfloat16(Bsh[r][n2]);
    Abuf[((size_t)bk * 64 + n2) * 128 + 64 + r] = __float2bfloat16(Csh[n2l][r]);
  }
}

// ---------------------------------------------------------------- S_loc GEMM: S[bk][c][n] (bf16) = cumA_T[c]*(wT@BtBuf^T)
__global__ __launch_bounds__(256, 4) void sloc_gemm_kernel(
    const __hip_bfloat16* __restrict__ wT, const __hip_bfloat16* __restrict__ BtBuf,
    const unsigned short* __restrict__ cumA, unsigned short* __restrict__ S) {
  __shared__ __align__(16) __hip_bfloat16 As[128 * 64];
  __shared__ __align__(16) __hip_bfloat16 Bs[64 * 64];
  const int tid = threadIdx.x;
  const int lane = tid & 63;
  const int w = tid >> 6;
  const int bk = blockIdx.x >> 4;
  const int ct = blockIdx.x & 15;
  const int b = bk >> 5, k = bk & 31;
  const int c0 = ct * 128;

  const int g8row = lane >> 3;
  const int scol = ((lane & 7) ^ g8row) * 8;
  const __hip_bfloat16* Ag = wT + ((size_t)bk * INNER + c0 + w * 32 + g8row) * 64 + scol;
  const __hip_bfloat16* Bg = BtBuf + ((size_t)bk * 64 + w * 16 + g8row) * 64 + scol;
  __hip_bfloat16* lA = As + (w * 32) * 64;
  __hip_bfloat16* lB = Bs + (w * 16) * 64;
#pragma unroll
  for (int g = 0; g < 4; ++g) gload16(Ag + (size_t)(g * 8) * 64, lA + (g * 8) * 64);
#pragma unroll
  for (int g = 0; g < 2; ++g) gload16(Bg + (size_t)(g * 8) * 64, lB + (g * 8) * 64);
  __syncthreads();

  const int lrow = lane & 15, lk = lane >> 4;
  f32x4 acc[2][4];
#pragma unroll
  for (int i = 0; i < 2; ++i)
#pragma unroll
    for (int j = 0; j < 4; ++j)
#pragma unroll
      for (int r2 = 0; r2 < 4; ++r2) acc[i][j][r2] = 0.f;

#pragma unroll
  for (int ss = 0; ss < 2; ++ss) {
    bf16x8 af[2], bv[4];
#pragma unroll
    for (int i = 0; i < 2; ++i) {
      const int ra = w * 32 + i * 16 + lrow;
      af[i] = *(const bf16x8*)(As + ra * 64 + (((ss * 4 + lk) ^ (ra & 7)) * 8));
    }
#pragma unroll
    for (int j = 0; j < 4; ++j) {
      const int rb = j * 16 + lrow;
      bv[j] = *(const bf16x8*)(Bs + rb * 64 + (((ss * 4 + lk) ^ (rb & 7)) * 8));
    }
#pragma unroll
    for (int i = 0; i < 2; ++i)
#pragma unroll
      for (int j = 0; j < 4; ++j)
        acc[i][j] = __builtin_amdgcn_mfma_f32_16x16x32_bf16(af[i], bv[j], acc[i][j], 0, 0, 0);
  }

  const size_t tokT = (size_t)(b * SEQ + k * TCHUNK + 63);
#pragma unroll
  for (int i = 0; i < 2; ++i) {
#pragma unroll
    for (int j = 0; j < 4; ++j) {
#pragma unroll
      for (int r2 = 0; r2 < 4; ++r2) {
        const int c = c0 + w * 32 + i * 16 + lk * 4 + r2;
        const int n = j * 16 + lrow;
        const float sc = bf2f(cumA[tokT * INNER + c]);
        S[((size_t)bk * INNER + c) * 64 + n] = f2bf(acc[i][j][r2] * sc);
      }
    }
  }
}

// ---------------------------------------------------------------- cross-chunk combine (in place, bf16 S)
__global__ __launch_bounds__(256) void scan_combine_kernel(
    unsigned short* __restrict__ S, const unsigned short* __restrict__ cumA) {
  const int idx = blockIdx.x * 256 + threadIdx.x;
  const int n = idx & 63;
  const int c = (idx >> 6) & (INNER - 1);
  const int b = idx >> 17;
  float s = 0.f;
  for (int k = 0; k < NCHUNK; ++k) {
    const size_t cs = (size_t)(b * NCHUNK + k) * INNER + c;
    const size_t off = cs * 64 + n;
    const float loc = bf2f(S[off]);
    S[off] = f2bf(s);
    const float ak = bf2f(cumA[((size_t)(b * SEQ + k * TCHUNK + 63)) * INNER + c]);
    s = fmaf(ak, s, loc);
  }
}

// ---------------------------------------------------------------- y GEMM: [trilG|C] @ [wT;S_in] -> epilogue
__global__ __launch_bounds__(256, 4) void ypre_gemm_kernel(
    const __hip_bfloat16* __restrict__ Abuf, const __hip_bfloat16* __restrict__ wT,
    const unsigned short* __restrict__ S, const unsigned short* __restrict__ cumA,
    const __hip_bfloat16* __restrict__ xch, const __hip_bfloat16* __restrict__ zbf,
    const float* __restrict__ Dv, __hip_bfloat16* __restrict__ ygated) {
  __shared__ __align__(16) __hip_bfloat16 Asm[64 * 128];   // [t][k]
  __shared__ __align__(16) __hip_bfloat16 Bsm[128 * 128];  // [c][k]
  const int tid = threadIdx.x;
  const int lane = tid & 63;
  const int w = tid >> 6;
  const int bk = blockIdx.x >> 4;
  const int ct = blockIdx.x & 15;
  const int b = bk >> 5, k = bk & 31;
  const int c0 = ct * 128;

  {
#pragma unroll
    for (int g = 0; g < 4; ++g) {
      const int base = w * 16 + g * 4;
      const int col16s = (lane & 15) ^ ((base + (lane >> 4)) & 7);
      const __hip_bfloat16* src =
          Abuf + ((size_t)bk * 64 + base + (lane >> 4)) * 128 + col16s * 8;
      gload16(src, (char*)Asm + base * 256);
    }
  }
  {
    const int row = tid & 127, part = tid >> 7;
    const int c = c0 + row;
    if (part == 0) {
      const uint4* src = (const uint4*)(wT + ((size_t)bk * INNER + c) * 64);
#pragma unroll
      for (int s2 = 0; s2 < 8; ++s2) {
        uint4 v = src[s2];
        *(uint4*)((char*)Bsm + row * 256 + (s2 ^ (row & 7)) * 16) = v;
      }
    } else {
      const uint4* srcS = (const uint4*)(S + ((size_t)bk * INNER + c) * 64);
#pragma unroll
      for (int s2 = 0; s2 < 8; ++s2) {
        uint4 v = srcS[s2];
        *(uint4*)((char*)Bsm + row * 256 + ((8 + s2) ^ (row & 7)) * 16) = v;
      }
    }
  }
  __syncthreads();

  const int lrow = lane & 15, lk = lane >> 4;
  f32x4 acc[8];
#pragma unroll
  for (int j = 0; j < 8; ++j)
#pragma unroll
    for (int r2 = 0; r2 < 4; ++r2) acc[j][r2] = 0.f;

  const int ra = w * 16 + lrow;
#pragma unroll
  for (int kk = 0; kk < 4; ++kk) {
    const int csa = (kk * 4 + lk) ^ (ra & 7);
    bf16x8 af = *(const bf16x8*)((const char*)Asm + ra * 256 + csa * 16);
#pragma unroll
    for (int j = 0; j < 8; ++j) {
      const int rb = j * 16 + lrow;
      const int csb = (kk * 4 + lk) ^ (rb & 7);
      bf16x8 bv = *(const bf16x8*)((const char*)Bsm + rb * 256 + csb * 16);
      acc[j] = __builtin_amdgcn_mfma_f32_16x16x32_bf16(af, bv, acc[j], 0, 0, 0);
    }
  }

  const size_t tokb = (size_t)(b * SEQ + k * TCHUNK);
#pragma unroll
  for (int j = 0; j < 8; ++j) {
#pragma unroll
    for (int r2 = 0; r2 < 4; ++r2) {
      const int t = w * 16 + lk * 4 + r2;
      const int c = c0 + j * 16 + lrow;
      const size_t tok = tokb + t;
      const float ca = bf2f(cumA[tok * INNER + c]);
      const float xc = bf2f(*(const unsigned short*)&xch[tok * LDI + c]);
      const float z = bf2f(*(const unsigned short*)&zbf[tok * LDI + c]);
      const float yt = ca * acc[j][r2] + Dv[c] * xc;
      const float g = z / (1.f + __expf(-z));
      *(unsigned short*)&ygated[tok * LDI + c] = f2bf(yt * g);
    }
  }
}

// ---------------------------------------------------------------- launch
extern "C" void kernel_launch(void* const* d_in, const int* in_sizes, int n_in,
                              void* d_out, int out_size, void* d_ws, size_t ws_size,
                              hipStream_t stream) {
  const float* x      = (const float*)d_in[0];
  const float* W_in   = (const float*)d_in[1];
  const float* conv_w = (const float*)d_in[2];
  const float* conv_b = (const float*)d_in[3];
  const float* W_dt   = (const float*)d_in[4];
  const float* b_dt   = (const float*)d_in[5];
  const float* W_B    = (const float*)d_in[6];
  const float* W_C    = (const float*)d_in[7];
  const float* Dvec   = (const float*)d_in[8];
  const float* W_out  = (const float*)d_in[9];
  float* out = (float*)d_out;

  char* p = (char*)d_ws;
  auto alloc = [&](size_t bytes) {
    char* r = p;
    p += (bytes + 255) & ~(size_t)255;
    return r;
  };
  __hip_bfloat16* xin   = (__hip_bfloat16*)alloc((size_t)NTOK * LDI * 2);  // later ygated
  __hip_bfloat16* zbf   = (__hip_bfloat16*)alloc((size_t)NTOK * LDI * 2);
  char*           scr   = alloc((size_t)NTOK * LDH * 2 + (size_t)2 * INNER * LDH * 2);
  __hip_bfloat16* WmidT = (__hip_bfloat16*)alloc((size_t)NMID * LDI * 2);
  __hip_bfloat16* WoutT = (__hip_bfloat16*)alloc((size_t)HID * LDI * 2);
  unsigned short* cumA  = (unsigned short*)alloc((size_t)NTOK * INNER * 2);
  __hip_bfloat16* wT    = (__hip_bfloat16*)alloc((size_t)BATCH * NCHUNK * INNER * TCHUNK * 2);
  __hip_bfloat16* Abuf  = (__hip_bfloat16*)alloc((size_t)BATCH * NCHUNK * 64 * 128 * 2);
  __hip_bfloat16* BtBuf = (__hip_bfloat16*)alloc((size_t)BATCH * NCHUNK * 64 * 64 * 2);
  __hip_bfloat16* Pmid  = (__hip_bfloat16*)alloc((size_t)2 * NTOK * NMID * 2);  // 35.7MB; later S / Pout

  __hip_bfloat16* x_bf   = (__hip_bfloat16*)scr;
  __hip_bfloat16* WinT   = (__hip_bfloat16*)(scr + (size_t)NTOK * LDH * 2);
  __hip_bfloat16* xch    = (__hip_bfloat16*)scr;
  __hip_bfloat16* ygated = xin;
  unsigned short* S      = (unsigned short*)Pmid;  // 16MB, after chunkG (last Pmid reader)
  __hip_bfloat16* Pout   = Pmid;                   // 33.5MB, after ypre

  // 1. conversions / transposes
  cvt_pad_kernel<<<(NTOK * HID / 4 + 255) / 256, 256, 0, stream>>>(x, x_bf, NTOK * HID / 4);
  transpose_cvt_kernel<<<dim3((2 * INNER) / 32, HID / 32), 256, 0, stream>>>(W_in, WinT, HID, 2 * INNER, LDH);
  transpose_cvt_kernel<<<dim3(INNER / 32, INNER / 32), 256, 0, stream>>>(W_dt, WmidT, INNER, INNER, LDI);
  transpose_cvt_kernel<<<dim3(NSTATE / 32, INNER / 32), 256, 0, stream>>>(
      W_B, WmidT + (size_t)INNER * LDI, INNER, NSTATE, LDI);
  transpose_cvt_kernel<<<dim3(NSTATE / 32, INNER / 32), 256, 0, stream>>>(
      W_C, WmidT + (size_t)(INNER + NSTATE) * LDI, INNER, NSTATE, LDI);
  transpose_cvt_kernel<<<dim3(HID / 32, INNER / 32), 256, 0, stream>>>(W_out, WoutT, INNER, HID, LDI);

  // 2. xz = x @ W_in -> split bf16 (xin | z)
  {
    const int gridN = (2 * INNER) / 128, nwg = (NTOK / 128) * gridN;
    gemm_bt_kernel<1><<<nwg, 256, 0, stream>>>(
        x_bf, WinT, NTOK, 2 * INNER, HID, LDH, gridN, nwg, nwg, nullptr, 0, LDI, xin, zbf);
  }

  // 3. conv + silu
  conv_silu_kernel<<<(NTOK * (INNER / 4)) / 256, 256, 0, stream>>>(xin, conv_w, conv_b, xch);

  // 4. mid GEMM split-K x2 (bf16 partials)
  {
    const int gridN = NMID / 128;
    const int mnwg = (NTOK / 128) * gridN;
    const int nwg = mnwg * 2;
    gemm_bt_kernel<2><<<nwg, 256, 0, stream>>>(
        xch, WmidT, NTOK, NMID, INNER / 2, LDI, gridN, nwg, mnwg, nullptr, NMID, 0,
        Pmid, nullptr);
  }

  // 5. chunked selective scan (GEMM form; cumv/chunkG consume partials directly)
  cumv_kernel<<<dim3(INNER / 256, BATCH * NCHUNK), 256, 0, stream>>>(
      Pmid, b_dt, xch, cumA, (unsigned int*)wT);
  chunkG_kernel<<<BATCH * NCHUNK * 4, 256, 0, stream>>>(Pmid, Abuf, BtBuf);
  sloc_gemm_kernel<<<BATCH * NCHUNK * 16, 256, 0, stream>>>(wT, BtBuf, cumA, S);
  scan_combine_kernel<<<(BATCH * INNER * NSTATE) / 256, 256, 0, stream>>>(S, cumA);
  ypre_gemm_kernel<<<BATCH * NCHUNK * 16, 256, 0, stream>>>(
      Abuf, wT, S, cumA, xch, zbf, Dvec, ygated);

  // 6. out = ygated @ W_out, split-K x4 (bf16 partials) + reduce
  {
    const int gridN = HID / 128;
    const int mnwg = (NTOK / 128) * gridN;
    const int nwg = mnwg * 4;
    gemm_bt_kernel<2><<<nwg, 256, 0, stream>>>(
        ygated, WoutT, NTOK, HID, INNER / 4, LDI, gridN, nwg, mnwg, nullptr, HID, 0,
        Pout, nullptr);
    const int n4 = NTOK * HID / 4;
    reduce4b_kernel<<<(n4 + 255) / 256, 256, 0, stream>>>(Pout, out, n4);
  }
}

// Round 18
// 294.484 us; speedup vs baseline: 1.2282x; 1.2282x over previous
//
#include <hip/hip_runtime.h>
#include <hip/hip_bf16.h>
#include <math.h>

#define BATCH  2
#define SEQ    2048
#define HID    1024
#define INNER  2048
#define NSTATE 64
#define NTOK   (BATCH * SEQ)
#define TCHUNK 64
#define NCHUNK (SEQ / TCHUNK)
#define NMID   (INNER + 2 * NSTATE)   // 2176
#define LDH    1056
#define LDI    2080

typedef __bf16 bf16x8 __attribute__((ext_vector_type(8)));
typedef float  f32x4  __attribute__((ext_vector_type(4)));

typedef const __attribute__((address_space(1))) char* gas_ptr;
typedef __attribute__((address_space(3))) char*       las_ptr;

__device__ __forceinline__ void gload16(const void* g, void* l) {
  __builtin_amdgcn_global_load_lds((gas_ptr)g, (las_ptr)l, 16, 0, 0);
}

__device__ __forceinline__ unsigned short f2bf(float f) {
  __hip_bfloat16 h = __float2bfloat16(f);
  return __builtin_bit_cast(unsigned short, h);
}
__device__ __forceinline__ float bf2f(unsigned short u) {
  unsigned int x = ((unsigned int)u) << 16;
  return __builtin_bit_cast(float, x);
}

// ---------------------------------------------------------------- cvt fp32->bf16 (padded rows)
__global__ __launch_bounds__(256) void cvt_pad_kernel(
    const float* __restrict__ in, __hip_bfloat16* __restrict__ out, int n4) {
  int i = blockIdx.x * 256 + threadIdx.x;
  if (i >= n4) return;
  const int r = i >> 8;
  const int c = (i & 255) * 4;
  float4 v = *(const float4*)&in[(size_t)r * HID + c];
  ushort4 u;
  u.x = f2bf(v.x); u.y = f2bf(v.y); u.z = f2bf(v.z); u.w = f2bf(v.w);
  *(ushort4*)&out[(size_t)r * LDH + c] = u;
}

// ------------------------------------------------- transpose fp32 [R][C] -> bf16 [C][ostride]
__global__ __launch_bounds__(256) void transpose_cvt_kernel(
    const float* __restrict__ in, __hip_bfloat16* __restrict__ out,
    int R, int C, int ostride) {
  __shared__ float tile[32][33];
  int tx = threadIdx.x & 31, ty = threadIdx.x >> 5;
  int c0 = blockIdx.x * 32, r0 = blockIdx.y * 32;
#pragma unroll
  for (int i = 0; i < 4; ++i)
    tile[ty + 8 * i][tx] = in[(size_t)(r0 + ty + 8 * i) * C + c0 + tx];
  __syncthreads();
#pragma unroll
  for (int i = 0; i < 4; ++i)
    out[(size_t)(c0 + ty + 8 * i) * ostride + r0 + tx] =
        __float2bfloat16(tile[tx][ty + 8 * i]);
}

// ---------------------------------------------------------------- GEMM (r12-proven: 128x128, BK=64)
// EPI 0: fp32 Cout. EPI 1: bf16 split xin|z. EPI 2: bf16 split-K partial to o0 (stride ldc).
template <int EPI>
__global__ __launch_bounds__(256, 4) void gemm_bt_kernel(
    const __hip_bfloat16* __restrict__ A, const __hip_bfloat16* __restrict__ Bt,
    int M, int N, int Klen, int ldk, int gridN, int nwg, int mnwg,
    float* __restrict__ Cout, int ldc, int ldo,
    __hip_bfloat16* __restrict__ o0, __hip_bfloat16* __restrict__ o1) {
  __shared__ __align__(16) __hip_bfloat16 As[128 * 64];
  __shared__ __align__(16) __hip_bfloat16 Bs[128 * 64];
  const int tid = threadIdx.x;
  const int lane = tid & 63;
  const int w = tid >> 6;
  const int wr = w >> 1, wc = w & 1;

  const int orig = blockIdx.x;
  const int q8 = nwg >> 3, r8 = nwg & 7;
  const int xcd = orig & 7, seq = orig >> 3;
  const int wg = (xcd < r8 ? xcd * (q8 + 1) : r8 * (q8 + 1) + (xcd - r8) * q8) + seq;
  const int kz = wg / mnwg;
  const int wgr = wg - kz * mnwg;
  const int m0 = (wgr / gridN) * 128;
  const int n0 = (wgr % gridN) * 128;

  const __hip_bfloat16* Ab = A + (size_t)kz * Klen;
  const __hip_bfloat16* Bb = Bt + (size_t)kz * Klen;

  f32x4 acc[4][4];
#pragma unroll
  for (int i = 0; i < 4; ++i)
#pragma unroll
    for (int j = 0; j < 4; ++j)
#pragma unroll
      for (int r2 = 0; r2 < 4; ++r2) acc[i][j][r2] = 0.f;

  const int g8row = lane >> 3;
  const int scol = ((lane & 7) ^ g8row) * 8;
  const __hip_bfloat16* Agp = Ab + (size_t)(m0 + w * 32 + g8row) * ldk + scol;
  const __hip_bfloat16* Bgp = Bb + (size_t)(n0 + w * 32 + g8row) * ldk + scol;
  __hip_bfloat16* lA = As + (w * 32) * 64;
  __hip_bfloat16* lB = Bs + (w * 32) * 64;

  const int lrow = lane & 15, lk = lane >> 4;
  const int arow0 = wr * 64 + lrow;
  const int brow0 = wc * 64 + lrow;

  const int nt = Klen >> 6;
  for (int t = 0; t < nt; ++t) {
    __syncthreads();
#pragma unroll
    for (int g = 0; g < 4; ++g) {
      gload16(Agp + (size_t)(g * 8) * ldk + t * 64, lA + (g * 8) * 64);
      gload16(Bgp + (size_t)(g * 8) * ldk + t * 64, lB + (g * 8) * 64);
    }
    __syncthreads();
#pragma unroll
    for (int ss = 0; ss < 2; ++ss) {
      bf16x8 af[4], bv[4];
#pragma unroll
      for (int i = 0; i < 4; ++i) {
        const int ra = arow0 + i * 16;
        af[i] = *(const bf16x8*)(As + ra * 64 + (((ss * 4 + lk) ^ (ra & 7)) * 8));
        const int rb = brow0 + i * 16;
        bv[i] = *(const bf16x8*)(Bs + rb * 64 + (((ss * 4 + lk) ^ (rb & 7)) * 8));
      }
#pragma unroll
      for (int i = 0; i < 4; ++i)
#pragma unroll
        for (int j = 0; j < 4; ++j)
          acc[i][j] = __builtin_amdgcn_mfma_f32_16x16x32_bf16(af[i], bv[j], acc[i][j], 0, 0, 0);
    }
  }

#pragma unroll
  for (int i = 0; i < 4; ++i) {
#pragma unroll
    for (int j = 0; j < 4; ++j) {
#pragma unroll
      for (int r2 = 0; r2 < 4; ++r2) {
        const int row = m0 + wr * 64 + i * 16 + lk * 4 + r2;
        const int col = n0 + wc * 64 + j * 16 + lrow;
        const float v = acc[i][j][r2];
        if constexpr (EPI == 0) {
          Cout[(size_t)kz * M * ldc + (size_t)row * ldc + col] = v;
        } else if constexpr (EPI == 1) {
          if (col < INNER) o0[(size_t)row * ldo + col] = __float2bfloat16(v);
          else             o1[(size_t)row * ldo + (col - INNER)] = __float2bfloat16(v);
        } else {
          o0[(size_t)kz * M * ldc + (size_t)row * ldc + col] = __float2bfloat16(v);
        }
      }
    }
  }
}

// ---------------------------------------------------------------- split-K4 reduce (bf16 partials -> fp32 out)
__global__ __launch_bounds__(256) void reduce4b_kernel(
    const __hip_bfloat16* __restrict__ P, float* __restrict__ out, int n4) {
  int i = blockIdx.x * 256 + threadIdx.x;
  if (i >= n4) return;
  float4 acc = make_float4(0.f, 0.f, 0.f, 0.f);
#pragma unroll
  for (int pp = 0; pp < 4; ++pp) {
    ushort4 u = ((const ushort4*)P)[(size_t)pp * n4 + i];
    acc.x += bf2f(u.x); acc.y += bf2f(u.y); acc.z += bf2f(u.z); acc.w += bf2f(u.w);
  }
  ((float4*)out)[i] = acc;
}

// ---------------------------------------------------------------- causal depthwise conv + silu
__global__ __launch_bounds__(256) void conv_silu_kernel(
    const __hip_bfloat16* __restrict__ xin, const float* __restrict__ cw,
    const float* __restrict__ cb, __hip_bfloat16* __restrict__ xch) {
  int idx = blockIdx.x * 256 + threadIdx.x;
  int cg = idx & 511;
  int tok = idx >> 9;
  int c = cg * 4;
  int l = tok & (SEQ - 1);
  float wv[4][4];
#pragma unroll
  for (int i = 0; i < 4; ++i) {
    float4 w = *(const float4*)&cw[(c + i) * 4];
    wv[i][0] = w.x; wv[i][1] = w.y; wv[i][2] = w.z; wv[i][3] = w.w;
  }
  float4 bias = *(const float4*)&cb[c];
  float r0 = bias.x, r1 = bias.y, r2 = bias.z, r3 = bias.w;
#pragma unroll
  for (int k = 0; k < 4; ++k) {
    const int d = 3 - k;
    if (l >= d) {
      ushort4 xv = *(const ushort4*)&xin[(size_t)(tok - d) * LDI + c];
      r0 = fmaf(bf2f(xv.x), wv[0][k], r0);
      r1 = fmaf(bf2f(xv.y), wv[1][k], r1);
      r2 = fmaf(bf2f(xv.z), wv[2][k], r2);
      r3 = fmaf(bf2f(xv.w), wv[3][k], r3);
    }
  }
  r0 = r0 / (1.f + __expf(-r0));
  r1 = r1 / (1.f + __expf(-r1));
  r2 = r2 / (1.f + __expf(-r2));
  r3 = r3 / (1.f + __expf(-r3));
  ushort4 u;
  u.x = f2bf(r0); u.y = f2bf(r1); u.z = f2bf(r2); u.w = f2bf(r3);
  *(ushort4*)&xch[(size_t)tok * LDI + c] = u;
}

// ---------------------------------------------------------------- cumv v2: LDS-staged P0+P1 -> softplus -> cumA + wT
// Block = 64 channels x 1 chunk. Coalesced ushort4 staging into LDS, then
// 4-threads-per-channel segmented scan with shfl prefix-product.
__global__ __launch_bounds__(256) void cumv_kernel(
    const __hip_bfloat16* __restrict__ P, const float* __restrict__ bdt,
    const __hip_bfloat16* __restrict__ xch,
    unsigned short* __restrict__ cumA, unsigned int* __restrict__ wT) {
  __shared__ float dpre[64][68];
  __shared__ float xcs[64][68];
  const int bk = blockIdx.y;
  const int c0 = blockIdx.x * 64;
  const int b = bk >> 5, k = bk & 31;
  const size_t tokbase = (size_t)(b * SEQ + k * TCHUNK);
  const unsigned short* P0 = (const unsigned short*)P;
  const unsigned short* P1 = P0 + (size_t)NTOK * NMID;
  const unsigned short* XC = (const unsigned short*)xch;

  // staging: thread (r0, g) covers rows r0+16*rr, channels c0+g*4..+3
  const int g = threadIdx.x & 15;
  const int r0 = threadIdx.x >> 4;
  const float4 bias4 = *(const float4*)&bdt[c0 + g * 4];
#pragma unroll
  for (int rr = 0; rr < 4; ++rr) {
    const int row = r0 + rr * 16;
    const size_t tok = tokbase + row;
    ushort4 u0 = *(const ushort4*)&P0[tok * NMID + c0 + g * 4];
    ushort4 u1 = *(const ushort4*)&P1[tok * NMID + c0 + g * 4];
    ushort4 ux = *(const ushort4*)&XC[tok * LDI + c0 + g * 4];
    float4 d = make_float4(bf2f(u0.x) + bf2f(u1.x) + bias4.x,
                           bf2f(u0.y) + bf2f(u1.y) + bias4.y,
                           bf2f(u0.z) + bf2f(u1.z) + bias4.z,
                           bf2f(u0.w) + bf2f(u1.w) + bias4.w);
    *(float4*)&dpre[row][g * 4] = d;
    *(float4*)&xcs[row][g * 4] = make_float4(bf2f(ux.x), bf2f(ux.y), bf2f(ux.z), bf2f(ux.w));
  }
  __syncthreads();

  // scan: channel cl, t-segment h (16 t each)
  const int cl = threadIdx.x >> 2, h = threadIdx.x & 3;
  const int c = c0 + cl;
  float dt[16], lc[16];
  float cum = 1.f;
#pragma unroll
  for (int j = 0; j < 16; ++j) {
    const int t = h * 16 + j;
    const float dp = dpre[t][cl];
    const float dtv = (dp > 15.f) ? dp : log1pf(__expf(dp));
    dt[j] = dtv;
    cum *= __expf(-dtv);
    lc[j] = cum;
  }
  const int lane = threadIdx.x & 63;
  const int gbase = lane & ~3;
  const float s0 = __shfl(cum, gbase + 0);
  const float s1 = __shfl(cum, gbase + 1);
  const float s2 = __shfl(cum, gbase + 2);
  float pre = 1.f;
  if (h > 0) pre *= s0;
  if (h > 1) pre *= s1;
  if (h > 2) pre *= s2;
  unsigned int wreg[8];
#pragma unroll
  for (int j = 0; j < 16; ++j) {
    const int t = h * 16 + j;
    const float cg = fmaxf(pre * lc[j], 1e-30f);
    cumA[(tokbase + t) * INNER + c] = f2bf(cg);
    const unsigned short wb = f2bf(dt[j] * xcs[t][cl] / cg);
    if (j & 1) wreg[j >> 1] |= ((unsigned int)wb) << 16;
    else       wreg[j >> 1] = (unsigned int)wb;
  }
  uint4* dst = (uint4*)(wT + ((size_t)bk * INNER + c) * 32 + h * 8);
  dst[0] = make_uint4(wreg[0], wreg[1], wreg[2], wreg[3]);
  dst[1] = make_uint4(wreg[4], wreg[5], wreg[6], wreg[7]);
}

// ---------------------------------------------------------------- chunkG: P(B|C cols) -> tril(C@B^T), C/B^T copies
// 4 blocks per chunk (t-quartered).
__global__ __launch_bounds__(256) void chunkG_kernel(
    const __hip_bfloat16* __restrict__ P,
    __hip_bfloat16* __restrict__ Abuf, __hip_bfloat16* __restrict__ BtBuf) {
  __shared__ float Bsh[TCHUNK][NSTATE + 4];
  __shared__ float Csh[16][NSTATE + 4];
  const int blk = blockIdx.x;
  const int bk = blk >> 2, qt = blk & 3;
  const int b = bk >> 5, k = bk & 31;
  const int tid = threadIdx.x;
  const size_t tokbase = (size_t)(b * SEQ + k * TCHUNK);
  const unsigned short* P0 = (const unsigned short*)P;
  const unsigned short* P1 = (const unsigned short*)P + (size_t)NTOK * NMID;

  for (int i = tid; i < TCHUNK * 16; i += 256) {
    const int row = i >> 4, q = i & 15;
    const size_t off = (tokbase + row) * NMID + INNER + q * 4;
    ushort4 u0 = *(const ushort4*)&P0[off];
    ushort4 u1 = *(const ushort4*)&P1[off];
    *(float4*)&Bsh[row][q * 4] = make_float4(
        bf2f(u0.x) + bf2f(u1.x), bf2f(u0.y) + bf2f(u1.y),
        bf2f(u0.z) + bf2f(u1.z), bf2f(u0.w) + bf2f(u1.w));
  }
  for (int i = tid; i < 16 * 16; i += 256) {
    const int row = i >> 4, q = i & 15;
    const size_t off = (tokbase + qt * 16 + row) * NMID + INNER + NSTATE + q * 4;
    ushort4 u0 = *(const ushort4*)&P0[off];
    ushort4 u1 = *(const ushort4*)&P1[off];
    *(float4*)&Csh[row][q * 4] = make_float4(
        bf2f(u0.x) + bf2f(u1.x), bf2f(u0.y) + bf2f(u1.y),
        bf2f(u0.z) + bf2f(u1.z), bf2f(u0.w) + bf2f(u1.w));
  }
  __syncthreads();
  for (int e = tid; e < 16 * 64; e += 256) {
    const int tl = e >> 6, tau = e & 63;
    const int t = qt * 16 + tl;
    float g = 0.f;
    if (tau <= t) {
#pragma unroll
      for (int q = 0; q < 16; ++q) {
        const float4 cv = *(const float4*)&Csh[tl][q * 4];
        const float4 bv = *(const float4*)&Bsh[tau][q * 4];
        g += cv.x * bv.x + cv.y * bv.y + cv.z * bv.z + cv.w * bv.w;
      }
    }
    Abuf[((size_t)bk * 64 + t) * 128 + tau] = __float2bfloat16(g);
  }
  for (int e = tid; e < 16 * 64; e += 256) {
    const int n2l = e >> 6, r = e & 63;
    const int n2 = qt * 16 + n2l;
    BtBuf[((size_t)bk * 64 + n2) * 64 + r] = __float2bfloat16(Bsh[r][n2]);
    Abuf[((size_t)bk * 64 + n2) * 128 + 64 + r] = __float2bfloat16(Csh[n2l][r]);
  }
}

// ---------------------------------------------------------------- S_loc GEMM: S[bk][c][n] (bf16) = cumA_T[c]*(wT@BtBuf^T)
__global__ __launch_bounds__(256, 4) void sloc_gemm_kernel(
    const __hip_bfloat16* __restrict__ wT, const __hip_bfloat16* __restrict__ BtBuf,
    const unsigned short* __restrict__ cumA, unsigned short* __restrict__ S) {
  __shared__ __align__(16) __hip_bfloat16 As[128 * 64];
  __shared__ __align__(16) __hip_bfloat16 Bs[64 * 64];
  const int tid = threadIdx.x;
  const int lane = tid & 63;
  const int w = tid >> 6;
  const int bk = blockIdx.x >> 4;
  const int ct = blockIdx.x & 15;
  const int b = bk >> 5, k = bk & 31;
  const int c0 = ct * 128;

  const int g8row = lane >> 3;
  const int scol = ((lane & 7) ^ g8row) * 8;
  const __hip_bfloat16* Ag = wT + ((size_t)bk * INNER + c0 + w * 32 + g8row) * 64 + scol;
  const __hip_bfloat16* Bg = BtBuf + ((size_t)bk * 64 + w * 16 + g8row) * 64 + scol;
  __hip_bfloat16* lA = As + (w * 32) * 64;
  __hip_bfloat16* lB = Bs + (w * 16) * 64;
#pragma unroll
  for (int g = 0; g < 4; ++g) gload16(Ag + (size_t)(g * 8) * 64, lA + (g * 8) * 64);
#pragma unroll
  for (int g = 0; g < 2; ++g) gload16(Bg + (size_t)(g * 8) * 64, lB + (g * 8) * 64);
  __syncthreads();

  const int lrow = lane & 15, lk = lane >> 4;
  f32x4 acc[2][4];
#pragma unroll
  for (int i = 0; i < 2; ++i)
#pragma unroll
    for (int j = 0; j < 4; ++j)
#pragma unroll
      for (int r2 = 0; r2 < 4; ++r2) acc[i][j][r2] = 0.f;

#pragma unroll
  for (int ss = 0; ss < 2; ++ss) {
    bf16x8 af[2], bv[4];
#pragma unroll
    for (int i = 0; i < 2; ++i) {
      const int ra = w * 32 + i * 16 + lrow;
      af[i] = *(const bf16x8*)(As + ra * 64 + (((ss * 4 + lk) ^ (ra & 7)) * 8));
    }
#pragma unroll
    for (int j = 0; j < 4; ++j) {
      const int rb = j * 16 + lrow;
      bv[j] = *(const bf16x8*)(Bs + rb * 64 + (((ss * 4 + lk) ^ (rb & 7)) * 8));
    }
#pragma unroll
    for (int i = 0; i < 2; ++i)
#pragma unroll
      for (int j = 0; j < 4; ++j)
        acc[i][j] = __builtin_amdgcn_mfma_f32_16x16x32_bf16(af[i], bv[j], acc[i][j], 0, 0, 0);
  }

  const size_t tokT = (size_t)(b * SEQ + k * TCHUNK + 63);
#pragma unroll
  for (int i = 0; i < 2; ++i) {
#pragma unroll
    for (int j = 0; j < 4; ++j) {
#pragma unroll
      for (int r2 = 0; r2 < 4; ++r2) {
        const int c = c0 + w * 32 + i * 16 + lk * 4 + r2;
        const int n = j * 16 + lrow;
        const float sc = bf2f(cumA[tokT * INNER + c]);
        S[((size_t)bk * INNER + c) * 64 + n] = f2bf(acc[i][j][r2] * sc);
      }
    }
  }
}

// ---------------------------------------------------------------- cross-chunk combine (in place, bf16 S)
__global__ __launch_bounds__(256) void scan_combine_kernel(
    unsigned short* __restrict__ S, const unsigned short* __restrict__ cumA) {
  const int idx = blockIdx.x * 256 + threadIdx.x;
  const int n = idx & 63;
  const int c = (idx >> 6) & (INNER - 1);
  const int b = idx >> 17;
  float s = 0.f;
  for (int k = 0; k < NCHUNK; ++k) {
    const size_t cs = (size_t)(b * NCHUNK + k) * INNER + c;
    const size_t off = cs * 64 + n;
    const float loc = bf2f(S[off]);
    S[off] = f2bf(s);
    const float ak = bf2f(cumA[((size_t)(b * SEQ + k * TCHUNK + 63)) * INNER + c]);
    s = fmaf(ak, s, loc);
  }
}

// ---------------------------------------------------------------- y GEMM: [trilG|C] @ [wT;S_in] -> epilogue
__global__ __launch_bounds__(256, 4) void ypre_gemm_kernel(
    const __hip_bfloat16* __restrict__ Abuf, const __hip_bfloat16* __restrict__ wT,
    const unsigned short* __restrict__ S, const unsigned short* __restrict__ cumA,
    const __hip_bfloat16* __restrict__ xch, const __hip_bfloat16* __restrict__ zbf,
    const float* __restrict__ Dv, __hip_bfloat16* __restrict__ ygated) {
  __shared__ __align__(16) __hip_bfloat16 Asm[64 * 128];   // [t][k]
  __shared__ __align__(16) __hip_bfloat16 Bsm[128 * 128];  // [c][k]
  const int tid = threadIdx.x;
  const int lane = tid & 63;
  const int w = tid >> 6;
  const int bk = blockIdx.x >> 4;
  const int ct = blockIdx.x & 15;
  const int b = bk >> 5, k = bk & 31;
  const int c0 = ct * 128;

  {
#pragma unroll
    for (int g = 0; g < 4; ++g) {
      const int base = w * 16 + g * 4;
      const int col16s = (lane & 15) ^ ((base + (lane >> 4)) & 7);
      const __hip_bfloat16* src =
          Abuf + ((size_t)bk * 64 + base + (lane >> 4)) * 128 + col16s * 8;
      gload16(src, (char*)Asm + base * 256);
    }
  }
  {
    const int row = tid & 127, part = tid >> 7;
    const int c = c0 + row;
    if (part == 0) {
      const uint4* src = (const uint4*)(wT + ((size_t)bk * INNER + c) * 64);
#pragma unroll
      for (int s2 = 0; s2 < 8; ++s2) {
        uint4 v = src[s2];
        *(uint4*)((char*)Bsm + row * 256 + (s2 ^ (row & 7)) * 16) = v;
      }
    } else {
      const uint4* srcS = (const uint4*)(S + ((size_t)bk * INNER + c) * 64);
#pragma unroll
      for (int s2 = 0; s2 < 8; ++s2) {
        uint4 v = srcS[s2];
        *(uint4*)((char*)Bsm + row * 256 + ((8 + s2) ^ (row & 7)) * 16) = v;
      }
    }
  }
  __syncthreads();

  const int lrow = lane & 15, lk = lane >> 4;
  f32x4 acc[8];
#pragma unroll
  for (int j = 0; j < 8; ++j)
#pragma unroll
    for (int r2 = 0; r2 < 4; ++r2) acc[j][r2] = 0.f;

  const int ra = w * 16 + lrow;
#pragma unroll
  for (int kk = 0; kk < 4; ++kk) {
    const int csa = (kk * 4 + lk) ^ (ra & 7);
    bf16x8 af = *(const bf16x8*)((const char*)Asm + ra * 256 + csa * 16);
#pragma unroll
    for (int j = 0; j < 8; ++j) {
      const int rb = j * 16 + lrow;
      const int csb = (kk * 4 + lk) ^ (rb & 7);
      bf16x8 bv = *(const bf16x8*)((const char*)Bsm + rb * 256 + csb * 16);
      acc[j] = __builtin_amdgcn_mfma_f32_16x16x32_bf16(af, bv, acc[j], 0, 0, 0);
    }
  }

  const size_t tokb = (size_t)(b * SEQ + k * TCHUNK);
#pragma unroll
  for (int j = 0; j < 8; ++j) {
#pragma unroll
    for (int r2 = 0; r2 < 4; ++r2) {
      const int t = w * 16 + lk * 4 + r2;
      const int c = c0 + j * 16 + lrow;
      const size_t tok = tokb + t;
      const float ca = bf2f(cumA[tok * INNER + c]);
      const float xc = bf2f(*(const unsigned short*)&xch[tok * LDI + c]);
      const float z = bf2f(*(const unsigned short*)&zbf[tok * LDI + c]);
      const float yt = ca * acc[j][r2] + Dv[c] * xc;
      const float g = z / (1.f + __expf(-z));
      *(unsigned short*)&ygated[tok * LDI + c] = f2bf(yt * g);
    }
  }
}

// ---------------------------------------------------------------- launch
extern "C" void kernel_launch(void* const* d_in, const int* in_sizes, int n_in,
                              void* d_out, int out_size, void* d_ws, size_t ws_size,
                              hipStream_t stream) {
  const float* x      = (const float*)d_in[0];
  const float* W_in   = (const float*)d_in[1];
  const float* conv_w = (const float*)d_in[2];
  const float* conv_b = (const float*)d_in[3];
  const float* W_dt   = (const float*)d_in[4];
  const float* b_dt   = (const float*)d_in[5];
  const float* W_B    = (const float*)d_in[6];
  const float* W_C    = (const float*)d_in[7];
  const float* Dvec   = (const float*)d_in[8];
  const float* W_out  = (const float*)d_in[9];
  float* out = (float*)d_out;

  char* p = (char*)d_ws;
  auto alloc = [&](size_t bytes) {
    char* r = p;
    p += (bytes + 255) & ~(size_t)255;
    return r;
  };
  __hip_bfloat16* xin   = (__hip_bfloat16*)alloc((size_t)NTOK * LDI * 2);  // later ygated
  __hip_bfloat16* zbf   = (__hip_bfloat16*)alloc((size_t)NTOK * LDI * 2);
  char*           scr   = alloc((size_t)NTOK * LDH * 2 + (size_t)2 * INNER * LDH * 2);
  __hip_bfloat16* WmidT = (__hip_bfloat16*)alloc((size_t)NMID * LDI * 2);
  __hip_bfloat16* WoutT = (__hip_bfloat16*)alloc((size_t)HID * LDI * 2);
  unsigned short* cumA  = (unsigned short*)alloc((size_t)NTOK * INNER * 2);
  __hip_bfloat16* wT    = (__hip_bfloat16*)alloc((size_t)BATCH * NCHUNK * INNER * TCHUNK * 2);
  __hip_bfloat16* Abuf  = (__hip_bfloat16*)alloc((size_t)BATCH * NCHUNK * 64 * 128 * 2);
  __hip_bfloat16* BtBuf = (__hip_bfloat16*)alloc((size_t)BATCH * NCHUNK * 64 * 64 * 2);
  __hip_bfloat16* Pmid  = (__hip_bfloat16*)alloc((size_t)2 * NTOK * NMID * 2);  // 35.7MB; later S / Pout

  __hip_bfloat16* x_bf   = (__hip_bfloat16*)scr;
  __hip_bfloat16* WinT   = (__hip_bfloat16*)(scr + (size_t)NTOK * LDH * 2);
  __hip_bfloat16* xch    = (__hip_bfloat16*)scr;
  __hip_bfloat16* ygated = xin;
  unsigned short* S      = (unsigned short*)Pmid;  // 16MB, after chunkG (last Pmid reader)
  __hip_bfloat16* Pout   = Pmid;                   // 33.5MB, after ypre

  // 1. conversions / transposes
  cvt_pad_kernel<<<(NTOK * HID / 4 + 255) / 256, 256, 0, stream>>>(x, x_bf, NTOK * HID / 4);
  transpose_cvt_kernel<<<dim3((2 * INNER) / 32, HID / 32), 256, 0, stream>>>(W_in, WinT, HID, 2 * INNER, LDH);
  transpose_cvt_kernel<<<dim3(INNER / 32, INNER / 32), 256, 0, stream>>>(W_dt, WmidT, INNER, INNER, LDI);
  transpose_cvt_kernel<<<dim3(NSTATE / 32, INNER / 32), 256, 0, stream>>>(
      W_B, WmidT + (size_t)INNER * LDI, INNER, NSTATE, LDI);
  transpose_cvt_kernel<<<dim3(NSTATE / 32, INNER / 32), 256, 0, stream>>>(
      W_C, WmidT + (size_t)(INNER + NSTATE) * LDI, INNER, NSTATE, LDI);
  transpose_cvt_kernel<<<dim3(HID / 32, INNER / 32), 256, 0, stream>>>(W_out, WoutT, INNER, HID, LDI);

  // 2. xz = x @ W_in -> split bf16 (xin | z)
  {
    const int gridN = (2 * INNER) / 128, nwg = (NTOK / 128) * gridN;
    gemm_bt_kernel<1><<<nwg, 256, 0, stream>>>(
        x_bf, WinT, NTOK, 2 * INNER, HID, LDH, gridN, nwg, nwg, nullptr, 0, LDI, xin, zbf);
  }

  // 3. conv + silu
  conv_silu_kernel<<<(NTOK * (INNER / 4)) / 256, 256, 0, stream>>>(xin, conv_w, conv_b, xch);

  // 4. mid GEMM split-K x2 (bf16 partials)
  {
    const int gridN = NMID / 128;
    const int mnwg = (NTOK / 128) * gridN;
    const int nwg = mnwg * 2;
    gemm_bt_kernel<2><<<nwg, 256, 0, stream>>>(
        xch, WmidT, NTOK, NMID, INNER / 2, LDI, gridN, nwg, mnwg, nullptr, NMID, 0,
        Pmid, nullptr);
  }

  // 5. chunked selective scan (GEMM form; cumv/chunkG consume partials directly)
  cumv_kernel<<<dim3(INNER / 64, BATCH * NCHUNK), 256, 0, stream>>>(
      Pmid, b_dt, xch, cumA, (unsigned int*)wT);
  chunkG_kernel<<<BATCH * NCHUNK * 4, 256, 0, stream>>>(Pmid, Abuf, BtBuf);
  sloc_gemm_kernel<<<BATCH * NCHUNK * 16, 256, 0, stream>>>(wT, BtBuf, cumA, S);
  scan_combine_kernel<<<(BATCH * INNER * NSTATE) / 256, 256, 0, stream>>>(S, cumA);
  ypre_gemm_kernel<<<BATCH * NCHUNK * 16, 256, 0, stream>>>(
      Abuf, wT, S, cumA, xch, zbf, Dvec, ygated);

  // 6. out = ygated @ W_out, split-K x4 (bf16 partials) + reduce
  {
    const int gridN = HID / 128;
    const int mnwg = (NTOK / 128) * gridN;
    const int nwg = mnwg * 4;
    gemm_bt_kernel<2><<<nwg, 256, 0, stream>>>(
        ygated, WoutT, NTOK, HID, INNER / 4, LDI, gridN, nwg, mnwg, nullptr, HID, 0,
        Pout, nullptr);
    const int n4 = NTOK * HID / 4;
    reduce4b_kernel<<<(n4 + 255) / 256, 256, 0, stream>>>(Pout, out, n4);
  }
}

// Round 19
// 285.863 us; speedup vs baseline: 1.2653x; 1.0302x over previous
//
#include <hip/hip_runtime.h>
#include <hip/hip_bf16.h>
#include <math.h>

#define BATCH  2
#define SEQ    2048
#define HID    1024
#define INNER  2048
#define NSTATE 64
#define NTOK   (BATCH * SEQ)
#define TCHUNK 64
#define NCHUNK (SEQ / TCHUNK)
#define NMID   (INNER + 2 * NSTATE)   // 2176
#define LDH    1056
#define LDI    2080

typedef __bf16 bf16x8 __attribute__((ext_vector_type(8)));
typedef float  f32x4  __attribute__((ext_vector_type(4)));

typedef const __attribute__((address_space(1))) char* gas_ptr;
typedef __attribute__((address_space(3))) char*       las_ptr;

__device__ __forceinline__ void gload16(const void* g, void* l) {
  __builtin_amdgcn_global_load_lds((gas_ptr)g, (las_ptr)l, 16, 0, 0);
}

__device__ __forceinline__ unsigned short f2bf(float f) {
  __hip_bfloat16 h = __float2bfloat16(f);
  return __builtin_bit_cast(unsigned short, h);
}
__device__ __forceinline__ float bf2f(unsigned short u) {
  unsigned int x = ((unsigned int)u) << 16;
  return __builtin_bit_cast(float, x);
}

// ---------------------------------------------------------------- cvt fp32->bf16 (padded rows)
__global__ __launch_bounds__(256) void cvt_pad_kernel(
    const float* __restrict__ in, __hip_bfloat16* __restrict__ out, int n4) {
  int i = blockIdx.x * 256 + threadIdx.x;
  if (i >= n4) return;
  const int r = i >> 8;
  const int c = (i & 255) * 4;
  float4 v = *(const float4*)&in[(size_t)r * HID + c];
  ushort4 u;
  u.x = f2bf(v.x); u.y = f2bf(v.y); u.z = f2bf(v.z); u.w = f2bf(v.w);
  *(ushort4*)&out[(size_t)r * LDH + c] = u;
}

// ------------------------------------------------- transpose fp32 [R][C] -> bf16 [C][ostride]
__global__ __launch_bounds__(256) void transpose_cvt_kernel(
    const float* __restrict__ in, __hip_bfloat16* __restrict__ out,
    int R, int C, int ostride) {
  __shared__ float tile[32][33];
  int tx = threadIdx.x & 31, ty = threadIdx.x >> 5;
  int c0 = blockIdx.x * 32, r0 = blockIdx.y * 32;
#pragma unroll
  for (int i = 0; i < 4; ++i)
    tile[ty + 8 * i][tx] = in[(size_t)(r0 + ty + 8 * i) * C + c0 + tx];
  __syncthreads();
#pragma unroll
  for (int i = 0; i < 4; ++i)
    out[(size_t)(c0 + ty + 8 * i) * ostride + r0 + tx] =
        __float2bfloat16(tile[tx][ty + 8 * i]);
}

// ---------------------------------------------------------------- GEMM (r12-proven: 128x128, BK=64)
// EPI 0: fp32 Cout. EPI 1: bf16 split xin|z. EPI 2: bf16 split-K partial to o0 (stride ldc).
template <int EPI>
__global__ __launch_bounds__(256, 4) void gemm_bt_kernel(
    const __hip_bfloat16* __restrict__ A, const __hip_bfloat16* __restrict__ Bt,
    int M, int N, int Klen, int ldk, int gridN, int nwg, int mnwg,
    float* __restrict__ Cout, int ldc, int ldo,
    __hip_bfloat16* __restrict__ o0, __hip_bfloat16* __restrict__ o1) {
  __shared__ __align__(16) __hip_bfloat16 As[128 * 64];
  __shared__ __align__(16) __hip_bfloat16 Bs[128 * 64];
  const int tid = threadIdx.x;
  const int lane = tid & 63;
  const int w = tid >> 6;
  const int wr = w >> 1, wc = w & 1;

  const int orig = blockIdx.x;
  const int q8 = nwg >> 3, r8 = nwg & 7;
  const int xcd = orig & 7, seq = orig >> 3;
  const int wg = (xcd < r8 ? xcd * (q8 + 1) : r8 * (q8 + 1) + (xcd - r8) * q8) + seq;
  const int kz = wg / mnwg;
  const int wgr = wg - kz * mnwg;
  const int m0 = (wgr / gridN) * 128;
  const int n0 = (wgr % gridN) * 128;

  const __hip_bfloat16* Ab = A + (size_t)kz * Klen;
  const __hip_bfloat16* Bb = Bt + (size_t)kz * Klen;

  f32x4 acc[4][4];
#pragma unroll
  for (int i = 0; i < 4; ++i)
#pragma unroll
    for (int j = 0; j < 4; ++j)
#pragma unroll
      for (int r2 = 0; r2 < 4; ++r2) acc[i][j][r2] = 0.f;

  const int g8row = lane >> 3;
  const int scol = ((lane & 7) ^ g8row) * 8;
  const __hip_bfloat16* Agp = Ab + (size_t)(m0 + w * 32 + g8row) * ldk + scol;
  const __hip_bfloat16* Bgp = Bb + (size_t)(n0 + w * 32 + g8row) * ldk + scol;
  __hip_bfloat16* lA = As + (w * 32) * 64;
  __hip_bfloat16* lB = Bs + (w * 32) * 64;

  const int lrow = lane & 15, lk = lane >> 4;
  const int arow0 = wr * 64 + lrow;
  const int brow0 = wc * 64 + lrow;

  const int nt = Klen >> 6;
  for (int t = 0; t < nt; ++t) {
    __syncthreads();
#pragma unroll
    for (int g = 0; g < 4; ++g) {
      gload16(Agp + (size_t)(g * 8) * ldk + t * 64, lA + (g * 8) * 64);
      gload16(Bgp + (size_t)(g * 8) * ldk + t * 64, lB + (g * 8) * 64);
    }
    __syncthreads();
#pragma unroll
    for (int ss = 0; ss < 2; ++ss) {
      bf16x8 af[4], bv[4];
#pragma unroll
      for (int i = 0; i < 4; ++i) {
        const int ra = arow0 + i * 16;
        af[i] = *(const bf16x8*)(As + ra * 64 + (((ss * 4 + lk) ^ (ra & 7)) * 8));
        const int rb = brow0 + i * 16;
        bv[i] = *(const bf16x8*)(Bs + rb * 64 + (((ss * 4 + lk) ^ (rb & 7)) * 8));
      }
#pragma unroll
      for (int i = 0; i < 4; ++i)
#pragma unroll
        for (int j = 0; j < 4; ++j)
          acc[i][j] = __builtin_amdgcn_mfma_f32_16x16x32_bf16(af[i], bv[j], acc[i][j], 0, 0, 0);
    }
  }

#pragma unroll
  for (int i = 0; i < 4; ++i) {
#pragma unroll
    for (int j = 0; j < 4; ++j) {
#pragma unroll
      for (int r2 = 0; r2 < 4; ++r2) {
        const int row = m0 + wr * 64 + i * 16 + lk * 4 + r2;
        const int col = n0 + wc * 64 + j * 16 + lrow;
        const float v = acc[i][j][r2];
        if constexpr (EPI == 0) {
          Cout[(size_t)kz * M * ldc + (size_t)row * ldc + col] = v;
        } else if constexpr (EPI == 1) {
          if (col < INNER) o0[(size_t)row * ldo + col] = __float2bfloat16(v);
          else             o1[(size_t)row * ldo + (col - INNER)] = __float2bfloat16(v);
        } else {
          o0[(size_t)kz * M * ldc + (size_t)row * ldc + col] = __float2bfloat16(v);
        }
      }
    }
  }
}

// ---------------------------------------------------------------- split-K4 reduce (bf16 partials -> fp32 out)
__global__ __launch_bounds__(256) void reduce4b_kernel(
    const __hip_bfloat16* __restrict__ P, float* __restrict__ out, int n4) {
  int i = blockIdx.x * 256 + threadIdx.x;
  if (i >= n4) return;
  float4 acc = make_float4(0.f, 0.f, 0.f, 0.f);
#pragma unroll
  for (int pp = 0; pp < 4; ++pp) {
    ushort4 u = ((const ushort4*)P)[(size_t)pp * n4 + i];
    acc.x += bf2f(u.x); acc.y += bf2f(u.y); acc.z += bf2f(u.z); acc.w += bf2f(u.w);
  }
  ((float4*)out)[i] = acc;
}

// ---------------------------------------------------------------- causal depthwise conv + silu
__global__ __launch_bounds__(256) void conv_silu_kernel(
    const __hip_bfloat16* __restrict__ xin, const float* __restrict__ cw,
    const float* __restrict__ cb, __hip_bfloat16* __restrict__ xch) {
  int idx = blockIdx.x * 256 + threadIdx.x;
  int cg = idx & 511;
  int tok = idx >> 9;
  int c = cg * 4;
  int l = tok & (SEQ - 1);
  float wv[4][4];
#pragma unroll
  for (int i = 0; i < 4; ++i) {
    float4 w = *(const float4*)&cw[(c + i) * 4];
    wv[i][0] = w.x; wv[i][1] = w.y; wv[i][2] = w.z; wv[i][3] = w.w;
  }
  float4 bias = *(const float4*)&cb[c];
  float r0 = bias.x, r1 = bias.y, r2 = bias.z, r3 = bias.w;
#pragma unroll
  for (int k = 0; k < 4; ++k) {
    const int d = 3 - k;
    if (l >= d) {
      ushort4 xv = *(const ushort4*)&xin[(size_t)(tok - d) * LDI + c];
      r0 = fmaf(bf2f(xv.x), wv[0][k], r0);
      r1 = fmaf(bf2f(xv.y), wv[1][k], r1);
      r2 = fmaf(bf2f(xv.z), wv[2][k], r2);
      r3 = fmaf(bf2f(xv.w), wv[3][k], r3);
    }
  }
  r0 = r0 / (1.f + __expf(-r0));
  r1 = r1 / (1.f + __expf(-r1));
  r2 = r2 / (1.f + __expf(-r2));
  r3 = r3 / (1.f + __expf(-r3));
  ushort4 u;
  u.x = f2bf(r0); u.y = f2bf(r1); u.z = f2bf(r2); u.w = f2bf(r3);
  *(ushort4*)&xch[(size_t)tok * LDI + c] = u;
}

// ---------------------------------------------------------------- cumv v3: LDS-staged, cumsum-of-dt, chunk-major cumT
// cumT[bk][c][t] bf16 = exp(-sum dt);  wT[bk][c][t] bf16 = dt*xc*exp(+sum dt).
// All global stores are coalesced uint4.
__global__ __launch_bounds__(256) void cumv_kernel(
    const __hip_bfloat16* __restrict__ P, const float* __restrict__ bdt,
    const __hip_bfloat16* __restrict__ xch,
    unsigned short* __restrict__ cumT, unsigned int* __restrict__ wT) {
  __shared__ float dpre[64][68];
  __shared__ float xcs[64][68];
  const int bk = blockIdx.y;
  const int c0 = blockIdx.x * 64;
  const int b = bk >> 5, k = bk & 31;
  const size_t tokbase = (size_t)(b * SEQ + k * TCHUNK);
  const unsigned short* P0 = (const unsigned short*)P;
  const unsigned short* P1 = P0 + (size_t)NTOK * NMID;
  const unsigned short* XC = (const unsigned short*)xch;

  // staging: thread (r0, g) covers rows r0+16*rr, channels c0+g*4..+3
  const int g = threadIdx.x & 15;
  const int r0 = threadIdx.x >> 4;
  const float4 bias4 = *(const float4*)&bdt[c0 + g * 4];
#pragma unroll
  for (int rr = 0; rr < 4; ++rr) {
    const int row = r0 + rr * 16;
    const size_t tok = tokbase + row;
    ushort4 u0 = *(const ushort4*)&P0[tok * NMID + c0 + g * 4];
    ushort4 u1 = *(const ushort4*)&P1[tok * NMID + c0 + g * 4];
    ushort4 ux = *(const ushort4*)&XC[tok * LDI + c0 + g * 4];
    float4 d = make_float4(bf2f(u0.x) + bf2f(u1.x) + bias4.x,
                           bf2f(u0.y) + bf2f(u1.y) + bias4.y,
                           bf2f(u0.z) + bf2f(u1.z) + bias4.z,
                           bf2f(u0.w) + bf2f(u1.w) + bias4.w);
    *(float4*)&dpre[row][g * 4] = d;
    *(float4*)&xcs[row][g * 4] = make_float4(bf2f(ux.x), bf2f(ux.y), bf2f(ux.z), bf2f(ux.w));
  }
  __syncthreads();

  // scan: channel cl, t-segment h (16 t each). cumsum of dt, prefix via shfl adds.
  const int cl = threadIdx.x >> 2, h = threadIdx.x & 3;
  const int c = c0 + cl;
  float dt[16], ls[16];
  float sdt = 0.f;
#pragma unroll
  for (int j = 0; j < 16; ++j) {
    const int t = h * 16 + j;
    const float dp = dpre[t][cl];
    const float dtv = (dp > 15.f) ? dp : log1pf(__expf(dp));
    dt[j] = dtv;
    sdt += dtv;
    ls[j] = sdt;
  }
  const int lane = threadIdx.x & 63;
  const int gbase = lane & ~3;
  const float s0 = __shfl(sdt, gbase + 0);
  const float s1 = __shfl(sdt, gbase + 1);
  const float s2 = __shfl(sdt, gbase + 2);
  float pre = 0.f;
  if (h > 0) pre += s0;
  if (h > 1) pre += s1;
  if (h > 2) pre += s2;
  unsigned int creg[8], wreg[8];
#pragma unroll
  for (int j = 0; j < 16; ++j) {
    const int t = h * 16 + j;
    const float st = fminf(pre + ls[j], 80.f);
    const float cg = __expf(-st);
    const float wi = __expf(st);
    const unsigned short cb = f2bf(cg);
    const unsigned short wb = f2bf(dt[j] * xcs[t][cl] * wi);
    if (j & 1) {
      creg[j >> 1] |= ((unsigned int)cb) << 16;
      wreg[j >> 1] |= ((unsigned int)wb) << 16;
    } else {
      creg[j >> 1] = (unsigned int)cb;
      wreg[j >> 1] = (unsigned int)wb;
    }
  }
  uint4* cd = (uint4*)((unsigned int*)cumT + ((size_t)bk * INNER + c) * 32 + h * 8);
  cd[0] = make_uint4(creg[0], creg[1], creg[2], creg[3]);
  cd[1] = make_uint4(creg[4], creg[5], creg[6], creg[7]);
  uint4* wd = (uint4*)(wT + ((size_t)bk * INNER + c) * 32 + h * 8);
  wd[0] = make_uint4(wreg[0], wreg[1], wreg[2], wreg[3]);
  wd[1] = make_uint4(wreg[4], wreg[5], wreg[6], wreg[7]);
}

// ---------------------------------------------------------------- chunkG: P(B|C cols) -> tril(C@B^T), C/B^T copies
// 4 blocks per chunk (t-quartered).
__global__ __launch_bounds__(256) void chunkG_kernel(
    const __hip_bfloat16* __restrict__ P,
    __hip_bfloat16* __restrict__ Abuf, __hip_bfloat16* __restrict__ BtBuf) {
  __shared__ float Bsh[TCHUNK][NSTATE + 4];
  __shared__ float Csh[16][NSTATE + 4];
  const int blk = blockIdx.x;
  const int bk = blk >> 2, qt = blk & 3;
  const int b = bk >> 5, k = bk & 31;
  const int tid = threadIdx.x;
  const size_t tokbase = (size_t)(b * SEQ + k * TCHUNK);
  const unsigned short* P0 = (const unsigned short*)P;
  const unsigned short* P1 = (const unsigned short*)P + (size_t)NTOK * NMID;

  for (int i = tid; i < TCHUNK * 16; i += 256) {
    const int row = i >> 4, q = i & 15;
    const size_t off = (tokbase + row) * NMID + INNER + q * 4;
    ushort4 u0 = *(const ushort4*)&P0[off];
    ushort4 u1 = *(const ushort4*)&P1[off];
    *(float4*)&Bsh[row][q * 4] = make_float4(
        bf2f(u0.x) + bf2f(u1.x), bf2f(u0.y) + bf2f(u1.y),
        bf2f(u0.z) + bf2f(u1.z), bf2f(u0.w) + bf2f(u1.w));
  }
  for (int i = tid; i < 16 * 16; i += 256) {
    const int row = i >> 4, q = i & 15;
    const size_t off = (tokbase + qt * 16 + row) * NMID + INNER + NSTATE + q * 4;
    ushort4 u0 = *(const ushort4*)&P0[off];
    ushort4 u1 = *(const ushort4*)&P1[off];
    *(float4*)&Csh[row][q * 4] = make_float4(
        bf2f(u0.x) + bf2f(u1.x), bf2f(u0.y) + bf2f(u1.y),
        bf2f(u0.z) + bf2f(u1.z), bf2f(u0.w) + bf2f(u1.w));
  }
  __syncthreads();
  for (int e = tid; e < 16 * 64; e += 256) {
    const int tl = e >> 6, tau = e & 63;
    const int t = qt * 16 + tl;
    float g = 0.f;
    if (tau <= t) {
#pragma unroll
      for (int q = 0; q < 16; ++q) {
        const float4 cv = *(const float4*)&Csh[tl][q * 4];
        const float4 bv = *(const float4*)&Bsh[tau][q * 4];
        g += cv.x * bv.x + cv.y * bv.y + cv.z * bv.z + cv.w * bv.w;
      }
    }
    Abuf[((size_t)bk * 64 + t) * 128 + tau] = __float2bfloat16(g);
  }
  for (int e = tid; e < 16 * 64; e += 256) {
    const int n2l = e >> 6, r = e & 63;
    const int n2 = qt * 16 + n2l;
    BtBuf[((size_t)bk * 64 + n2) * 64 + r] = __float2bfloat16(Bsh[r][n2]);
    Abuf[((size_t)bk * 64 + n2) * 128 + 64 + r] = __float2bfloat16(Csh[n2l][r]);
  }
}

// ---------------------------------------------------------------- S_loc GEMM: S[bk][c][n] (bf16) = cumT[c][63]*(wT@BtBuf^T)
__global__ __launch_bounds__(256, 4) void sloc_gemm_kernel(
    const __hip_bfloat16* __restrict__ wT, const __hip_bfloat16* __restrict__ BtBuf,
    const unsigned short* __restrict__ cumT, unsigned short* __restrict__ S) {
  __shared__ __align__(16) __hip_bfloat16 As[128 * 64];
  __shared__ __align__(16) __hip_bfloat16 Bs[64 * 64];
  const int tid = threadIdx.x;
  const int lane = tid & 63;
  const int w = tid >> 6;
  const int bk = blockIdx.x >> 4;
  const int ct = blockIdx.x & 15;
  const int c0 = ct * 128;

  const int g8row = lane >> 3;
  const int scol = ((lane & 7) ^ g8row) * 8;
  const __hip_bfloat16* Ag = wT + ((size_t)bk * INNER + c0 + w * 32 + g8row) * 64 + scol;
  const __hip_bfloat16* Bg = BtBuf + ((size_t)bk * 64 + w * 16 + g8row) * 64 + scol;
  __hip_bfloat16* lA = As + (w * 32) * 64;
  __hip_bfloat16* lB = Bs + (w * 16) * 64;
#pragma unroll
  for (int g = 0; g < 4; ++g) gload16(Ag + (size_t)(g * 8) * 64, lA + (g * 8) * 64);
#pragma unroll
  for (int g = 0; g < 2; ++g) gload16(Bg + (size_t)(g * 8) * 64, lB + (g * 8) * 64);
  __syncthreads();

  const int lrow = lane & 15, lk = lane >> 4;
  f32x4 acc[2][4];
#pragma unroll
  for (int i = 0; i < 2; ++i)
#pragma unroll
    for (int j = 0; j < 4; ++j)
#pragma unroll
      for (int r2 = 0; r2 < 4; ++r2) acc[i][j][r2] = 0.f;

#pragma unroll
  for (int ss = 0; ss < 2; ++ss) {
    bf16x8 af[2], bv[4];
#pragma unroll
    for (int i = 0; i < 2; ++i) {
      const int ra = w * 32 + i * 16 + lrow;
      af[i] = *(const bf16x8*)(As + ra * 64 + (((ss * 4 + lk) ^ (ra & 7)) * 8));
    }
#pragma unroll
    for (int j = 0; j < 4; ++j) {
      const int rb = j * 16 + lrow;
      bv[j] = *(const bf16x8*)(Bs + rb * 64 + (((ss * 4 + lk) ^ (rb & 7)) * 8));
    }
#pragma unroll
    for (int i = 0; i < 2; ++i)
#pragma unroll
      for (int j = 0; j < 4; ++j)
        acc[i][j] = __builtin_amdgcn_mfma_f32_16x16x32_bf16(af[i], bv[j], acc[i][j], 0, 0, 0);
  }

#pragma unroll
  for (int i = 0; i < 2; ++i) {
#pragma unroll
    for (int j = 0; j < 4; ++j) {
#pragma unroll
      for (int r2 = 0; r2 < 4; ++r2) {
        const int c = c0 + w * 32 + i * 16 + lk * 4 + r2;
        const int n = j * 16 + lrow;
        const float sc = bf2f(cumT[((size_t)bk * INNER + c) * 64 + 63]);
        S[((size_t)bk * INNER + c) * 64 + n] = f2bf(acc[i][j][r2] * sc);
      }
    }
  }
}

// ---------------------------------------------------------------- cross-chunk combine (in place, bf16 S)
__global__ __launch_bounds__(256) void scan_combine_kernel(
    unsigned short* __restrict__ S, const unsigned short* __restrict__ cumT) {
  const int idx = blockIdx.x * 256 + threadIdx.x;
  const int n = idx & 63;
  const int c = (idx >> 6) & (INNER - 1);
  const int b = idx >> 17;
  float s = 0.f;
  for (int k = 0; k < NCHUNK; ++k) {
    const size_t cs = (size_t)(b * NCHUNK + k) * INNER + c;
    const size_t off = cs * 64 + n;
    const float loc = bf2f(S[off]);
    S[off] = f2bf(s);
    const float ak = bf2f(cumT[cs * 64 + 63]);
    s = fmaf(ak, s, loc);
  }
}

// ---------------------------------------------------------------- y GEMM: [trilG|C] @ [wT;S_in] -> epilogue
__global__ __launch_bounds__(256, 4) void ypre_gemm_kernel(
    const __hip_bfloat16* __restrict__ Abuf, const __hip_bfloat16* __restrict__ wT,
    const unsigned short* __restrict__ S, const unsigned short* __restrict__ cumT,
    const __hip_bfloat16* __restrict__ xch, const __hip_bfloat16* __restrict__ zbf,
    const float* __restrict__ Dv, __hip_bfloat16* __restrict__ ygated) {
  __shared__ __align__(16) __hip_bfloat16 Asm[64 * 128];   // [t][k]
  __shared__ __align__(16) __hip_bfloat16 Bsm[128 * 128];  // [c][k]
  const int tid = threadIdx.x;
  const int lane = tid & 63;
  const int w = tid >> 6;
  const int bk = blockIdx.x >> 4;
  const int ct = blockIdx.x & 15;
  const int b = bk >> 5, k = bk & 31;
  const int c0 = ct * 128;

  {
#pragma unroll
    for (int g = 0; g < 4; ++g) {
      const int base = w * 16 + g * 4;
      const int col16s = (lane & 15) ^ ((base + (lane >> 4)) & 7);
      const __hip_bfloat16* src =
          Abuf + ((size_t)bk * 64 + base + (lane >> 4)) * 128 + col16s * 8;
      gload16(src, (char*)Asm + base * 256);
    }
  }
  {
    const int row = tid & 127, part = tid >> 7;
    const int c = c0 + row;
    if (part == 0) {
      const uint4* src = (const uint4*)(wT + ((size_t)bk * INNER + c) * 64);
#pragma unroll
      for (int s2 = 0; s2 < 8; ++s2) {
        uint4 v = src[s2];
        *(uint4*)((char*)Bsm + row * 256 + (s2 ^ (row & 7)) * 16) = v;
      }
    } else {
      const uint4* srcS = (const uint4*)(S + ((size_t)bk * INNER + c) * 64);
#pragma unroll
      for (int s2 = 0; s2 < 8; ++s2) {
        uint4 v = srcS[s2];
        *(uint4*)((char*)Bsm + row * 256 + ((8 + s2) ^ (row & 7)) * 16) = v;
      }
    }
  }
  __syncthreads();

  const int lrow = lane & 15, lk = lane >> 4;
  f32x4 acc[8];
#pragma unroll
  for (int j = 0; j < 8; ++j)
#pragma unroll
    for (int r2 = 0; r2 < 4; ++r2) acc[j][r2] = 0.f;

  const int ra = w * 16 + lrow;
#pragma unroll
  for (int kk = 0; kk < 4; ++kk) {
    const int csa = (kk * 4 + lk) ^ (ra & 7);
    bf16x8 af = *(const bf16x8*)((const char*)Asm + ra * 256 + csa * 16);
#pragma unroll
    for (int j = 0; j < 8; ++j) {
      const int rb = j * 16 + lrow;
      const int csb = (kk * 4 + lk) ^ (rb & 7);
      bf16x8 bv = *(const bf16x8*)((const char*)Bsm + rb * 256 + csb * 16);
      acc[j] = __builtin_amdgcn_mfma_f32_16x16x32_bf16(af, bv, acc[j], 0, 0, 0);
    }
  }

  const size_t tokb = (size_t)(b * SEQ + k * TCHUNK);
#pragma unroll
  for (int j = 0; j < 8; ++j) {
    const int c = c0 + j * 16 + lrow;
    const unsigned short* cp = cumT + ((size_t)bk * INNER + c) * 64 + w * 16 + lk * 4;
#pragma unroll
    for (int r2 = 0; r2 < 4; ++r2) {
      const int t = w * 16 + lk * 4 + r2;
      const size_t tok = tokb + t;
      const float ca = bf2f(cp[r2]);
      const float xc = bf2f(*(const unsigned short*)&xch[tok * LDI + c]);
      const float z = bf2f(*(const unsigned short*)&zbf[tok * LDI + c]);
      const float yt = ca * acc[j][r2] + Dv[c] * xc;
      const float g = z / (1.f + __expf(-z));
      *(unsigned short*)&ygated[tok * LDI + c] = f2bf(yt * g);
    }
  }
}

// ---------------------------------------------------------------- launch
extern "C" void kernel_launch(void* const* d_in, const int* in_sizes, int n_in,
                              void* d_out, int out_size, void* d_ws, size_t ws_size,
                              hipStream_t stream) {
  const float* x      = (const float*)d_in[0];
  const float* W_in   = (const float*)d_in[1];
  const float* conv_w = (const float*)d_in[2];
  const float* conv_b = (const float*)d_in[3];
  const float* W_dt   = (const float*)d_in[4];
  const float* b_dt   = (const float*)d_in[5];
  const float* W_B    = (const float*)d_in[6];
  const float* W_C    = (const float*)d_in[7];
  const float* Dvec   = (const float*)d_in[8];
  const float* W_out  = (const float*)d_in[9];
  float* out = (float*)d_out;

  char* p = (char*)d_ws;
  auto alloc = [&](size_t bytes) {
    char* r = p;
    p += (bytes + 255) & ~(size_t)255;
    return r;
  };
  __hip_bfloat16* xin   = (__hip_bfloat16*)alloc((size_t)NTOK * LDI * 2);  // later ygated
  __hip_bfloat16* zbf   = (__hip_bfloat16*)alloc((size_t)NTOK * LDI * 2);
  char*           scr   = alloc((size_t)NTOK * LDH * 2 + (size_t)2 * INNER * LDH * 2);
  __hip_bfloat16* WmidT = (__hip_bfloat16*)alloc((size_t)NMID * LDI * 2);
  __hip_bfloat16* WoutT = (__hip_bfloat16*)alloc((size_t)HID * LDI * 2);
  unsigned short* cumT  = (unsigned short*)alloc((size_t)BATCH * NCHUNK * INNER * TCHUNK * 2);
  __hip_bfloat16* wT    = (__hip_bfloat16*)alloc((size_t)BATCH * NCHUNK * INNER * TCHUNK * 2);
  __hip_bfloat16* Abuf  = (__hip_bfloat16*)alloc((size_t)BATCH * NCHUNK * 64 * 128 * 2);
  __hip_bfloat16* BtBuf = (__hip_bfloat16*)alloc((size_t)BATCH * NCHUNK * 64 * 64 * 2);
  __hip_bfloat16* Pmid  = (__hip_bfloat16*)alloc((size_t)2 * NTOK * NMID * 2);  // 35.7MB; later S / Pout

  __hip_bfloat16* x_bf   = (__hip_bfloat16*)scr;
  __hip_bfloat16* WinT   = (__hip_bfloat16*)(scr + (size_t)NTOK * LDH * 2);
  __hip_bfloat16* xch    = (__hip_bfloat16*)scr;
  __hip_bfloat16* ygated = xin;
  unsigned short* S      = (unsigned short*)Pmid;  // 16MB, after chunkG (last Pmid reader)
  __hip_bfloat16* Pout   = Pmid;                   // 33.5MB, after ypre

  // 1. conversions / transposes
  cvt_pad_kernel<<<(NTOK * HID / 4 + 255) / 256, 256, 0, stream>>>(x, x_bf, NTOK * HID / 4);
  transpose_cvt_kernel<<<dim3((2 * INNER) / 32, HID / 32), 256, 0, stream>>>(W_in, WinT, HID, 2 * INNER, LDH);
  transpose_cvt_kernel<<<dim3(INNER / 32, INNER / 32), 256, 0, stream>>>(W_dt, WmidT, INNER, INNER, LDI);
  transpose_cvt_kernel<<<dim3(NSTATE / 32, INNER / 32), 256, 0, stream>>>(
      W_B, WmidT + (size_t)INNER * LDI, INNER, NSTATE, LDI);
  transpose_cvt_kernel<<<dim3(NSTATE / 32, INNER / 32), 256, 0, stream>>>(
      W_C, WmidT + (size_t)(INNER + NSTATE) * LDI, INNER, NSTATE, LDI);
  transpose_cvt_kernel<<<dim3(HID / 32, INNER / 32), 256, 0, stream>>>(W_out, WoutT, INNER, HID, LDI);

  // 2. xz = x @ W_in -> split bf16 (xin | z)
  {
    const int gridN = (2 * INNER) / 128, nwg = (NTOK / 128) * gridN;
    gemm_bt_kernel<1><<<nwg, 256, 0, stream>>>(
        x_bf, WinT, NTOK, 2 * INNER, HID, LDH, gridN, nwg, nwg, nullptr, 0, LDI, xin, zbf);
  }

  // 3. conv + silu
  conv_silu_kernel<<<(NTOK * (INNER / 4)) / 256, 256, 0, stream>>>(xin, conv_w, conv_b, xch);

  // 4. mid GEMM split-K x2 (bf16 partials)
  {
    const int gridN = NMID / 128;
    const int mnwg = (NTOK / 128) * gridN;
    const int nwg = mnwg * 2;
    gemm_bt_kernel<2><<<nwg, 256, 0, stream>>>(
        xch, WmidT, NTOK, NMID, INNER / 2, LDI, gridN, nwg, mnwg, nullptr, NMID, 0,
        Pmid, nullptr);
  }

  // 5. chunked selective scan (GEMM form)
  cumv_kernel<<<dim3(INNER / 64, BATCH * NCHUNK), 256, 0, stream>>>(
      Pmid, b_dt, xch, cumT, (unsigned int*)wT);
  chunkG_kernel<<<BATCH * NCHUNK * 4, 256, 0, stream>>>(Pmid, Abuf, BtBuf);
  sloc_gemm_kernel<<<BATCH * NCHUNK * 16, 256, 0, stream>>>(wT, BtBuf, cumT, S);
  scan_combine_kernel<<<(BATCH * INNER * NSTATE) / 256, 256, 0, stream>>>(S, cumT);
  ypre_gemm_kernel<<<BATCH * NCHUNK * 16, 256, 0, stream>>>(
      Abuf, wT, S, cumT, xch, zbf, Dvec, ygated);

  // 6. out = ygated @ W_out, split-K x4 (bf16 partials) + reduce
  {
    const int gridN = HID / 128;
    const int mnwg = (NTOK / 128) * gridN;
    const int nwg = mnwg * 4;
    gemm_bt_kernel<2><<<nwg, 256, 0, stream>>>(
        ygated, WoutT, NTOK, HID, INNER / 4, LDI, gridN, nwg, mnwg, nullptr, HID, 0,
        Pout, nullptr);
    const int n4 = NTOK * HID / 4;
    reduce4b_kernel<<<(n4 + 255) / 256, 256, 0, stream>>>(Pout, out, n4);
  }
}

// Round 20
// 270.365 us; speedup vs baseline: 1.3378x; 1.0573x over previous
//
#include <hip/hip_runtime.h>
#include <hip/hip_bf16.h>
#include <math.h>

#define BATCH  2
#define SEQ    2048
#define HID    1024
#define INNER  2048
#define NSTATE 64
#define NTOK   (BATCH * SEQ)
#define TCHUNK 64
#define NCHUNK (SEQ / TCHUNK)
#define NMID   (INNER + 2 * NSTATE)   // 2176
#define LDH    1056
#define LDI    2080

typedef __bf16 bf16x8 __attribute__((ext_vector_type(8)));
typedef float  f32x4  __attribute__((ext_vector_type(4)));

typedef const __attribute__((address_space(1))) char* gas_ptr;
typedef __attribute__((address_space(3))) char*       las_ptr;

__device__ __forceinline__ void gload16(const void* g, void* l) {
  __builtin_amdgcn_global_load_lds((gas_ptr)g, (las_ptr)l, 16, 0, 0);
}

__device__ __forceinline__ unsigned short f2bf(float f) {
  __hip_bfloat16 h = __float2bfloat16(f);
  return __builtin_bit_cast(unsigned short, h);
}
__device__ __forceinline__ float bf2f(unsigned short u) {
  unsigned int x = ((unsigned int)u) << 16;
  return __builtin_bit_cast(float, x);
}

// ---------------------------------------------------------------- prep: all weight transposes + x cvt, one launch
// jobs: [0] W_in->WinT  [1] W_dt->WmidT  [2] W_B  [3] W_C  [4] W_out->WoutT  [5] cvt_pad(x)
#define NB_WIN  4096   // (2*INNER/32)*(HID/32)
#define NB_WDT  4096   // (INNER/32)*(INNER/32)
#define NB_WB   128    // (NSTATE/32)*(INNER/32)
#define NB_WC   128
#define NB_WOUT 2048   // (HID/32)*(INNER/32)
#define NB_CVT  4096   // NTOK*HID/4/256
#define OFF_WDT  (NB_WIN)
#define OFF_WB   (OFF_WDT + NB_WDT)
#define OFF_WC   (OFF_WB + NB_WB)
#define OFF_WOUT (OFF_WC + NB_WC)
#define OFF_CVT  (OFF_WOUT + NB_WOUT)
#define NB_PREP  (OFF_CVT + NB_CVT)

__device__ __forceinline__ void do_transpose(
    const float* __restrict__ in, __hip_bfloat16* __restrict__ out,
    int C, int ostride, int local, int nbx) {
  __shared__ float tile[32][33];
  const int tx = threadIdx.x & 31, ty = threadIdx.x >> 5;
  const int bx = local % nbx, by = local / nbx;
  const int c0 = bx * 32, r0 = by * 32;
#pragma unroll
  for (int i = 0; i < 4; ++i)
    tile[ty + 8 * i][tx] = in[(size_t)(r0 + ty + 8 * i) * C + c0 + tx];
  __syncthreads();
#pragma unroll
  for (int i = 0; i < 4; ++i)
    out[(size_t)(c0 + ty + 8 * i) * ostride + r0 + tx] =
        __float2bfloat16(tile[tx][ty + 8 * i]);
}

__global__ __launch_bounds__(256) void prep_kernel(
    const float* __restrict__ W_in, const float* __restrict__ W_dt,
    const float* __restrict__ W_B, const float* __restrict__ W_C,
    const float* __restrict__ W_out, const float* __restrict__ x,
    __hip_bfloat16* __restrict__ WinT, __hip_bfloat16* __restrict__ WmidT,
    __hip_bfloat16* __restrict__ WoutT, __hip_bfloat16* __restrict__ x_bf) {
  const int id = blockIdx.x;
  if (id < OFF_WDT) {
    do_transpose(W_in, WinT, 2 * INNER, LDH, id, (2 * INNER) / 32);
  } else if (id < OFF_WB) {
    do_transpose(W_dt, WmidT, INNER, LDI, id - OFF_WDT, INNER / 32);
  } else if (id < OFF_WC) {
    do_transpose(W_B, WmidT + (size_t)INNER * LDI, NSTATE, LDI, id - OFF_WB, NSTATE / 32);
  } else if (id < OFF_WOUT) {
    do_transpose(W_C, WmidT + (size_t)(INNER + NSTATE) * LDI, NSTATE, LDI, id - OFF_WC, NSTATE / 32);
  } else if (id < OFF_CVT) {
    do_transpose(W_out, WoutT, HID, LDI, id - OFF_WOUT, HID / 32);
  } else {
    const int i = (id - OFF_CVT) * 256 + threadIdx.x;
    const int r = i >> 8;
    const int c = (i & 255) * 4;
    float4 v = *(const float4*)&x[(size_t)r * HID + c];
    ushort4 u;
    u.x = f2bf(v.x); u.y = f2bf(v.y); u.z = f2bf(v.z); u.w = f2bf(v.w);
    *(ushort4*)&x_bf[(size_t)r * LDH + c] = u;
  }
}

// ---------------------------------------------------------------- GEMM (r12-proven: 128x128, BK=64)
// EPI 0: fp32 Cout. EPI 1: bf16 split xin|z. EPI 2: bf16 split-K partial to o0 (stride ldc).
template <int EPI>
__global__ __launch_bounds__(256, 4) void gemm_bt_kernel(
    const __hip_bfloat16* __restrict__ A, const __hip_bfloat16* __restrict__ Bt,
    int M, int N, int Klen, int ldk, int gridN, int nwg, int mnwg,
    float* __restrict__ Cout, int ldc, int ldo,
    __hip_bfloat16* __restrict__ o0, __hip_bfloat16* __restrict__ o1) {
  __shared__ __align__(16) __hip_bfloat16 As[128 * 64];
  __shared__ __align__(16) __hip_bfloat16 Bs[128 * 64];
  const int tid = threadIdx.x;
  const int lane = tid & 63;
  const int w = tid >> 6;
  const int wr = w >> 1, wc = w & 1;

  const int orig = blockIdx.x;
  const int q8 = nwg >> 3, r8 = nwg & 7;
  const int xcd = orig & 7, seq = orig >> 3;
  const int wg = (xcd < r8 ? xcd * (q8 + 1) : r8 * (q8 + 1) + (xcd - r8) * q8) + seq;
  const int kz = wg / mnwg;
  const int wgr = wg - kz * mnwg;
  const int m0 = (wgr / gridN) * 128;
  const int n0 = (wgr % gridN) * 128;

  const __hip_bfloat16* Ab = A + (size_t)kz * Klen;
  const __hip_bfloat16* Bb = Bt + (size_t)kz * Klen;

  f32x4 acc[4][4];
#pragma unroll
  for (int i = 0; i < 4; ++i)
#pragma unroll
    for (int j = 0; j < 4; ++j)
#pragma unroll
      for (int r2 = 0; r2 < 4; ++r2) acc[i][j][r2] = 0.f;

  const int g8row = lane >> 3;
  const int scol = ((lane & 7) ^ g8row) * 8;
  const __hip_bfloat16* Agp = Ab + (size_t)(m0 + w * 32 + g8row) * ldk + scol;
  const __hip_bfloat16* Bgp = Bb + (size_t)(n0 + w * 32 + g8row) * ldk + scol;
  __hip_bfloat16* lA = As + (w * 32) * 64;
  __hip_bfloat16* lB = Bs + (w * 32) * 64;

  const int lrow = lane & 15, lk = lane >> 4;
  const int arow0 = wr * 64 + lrow;
  const int brow0 = wc * 64 + lrow;

  const int nt = Klen >> 6;
  for (int t = 0; t < nt; ++t) {
    __syncthreads();
#pragma unroll
    for (int g = 0; g < 4; ++g) {
      gload16(Agp + (size_t)(g * 8) * ldk + t * 64, lA + (g * 8) * 64);
      gload16(Bgp + (size_t)(g * 8) * ldk + t * 64, lB + (g * 8) * 64);
    }
    __syncthreads();
#pragma unroll
    for (int ss = 0; ss < 2; ++ss) {
      bf16x8 af[4], bv[4];
#pragma unroll
      for (int i = 0; i < 4; ++i) {
        const int ra = arow0 + i * 16;
        af[i] = *(const bf16x8*)(As + ra * 64 + (((ss * 4 + lk) ^ (ra & 7)) * 8));
        const int rb = brow0 + i * 16;
        bv[i] = *(const bf16x8*)(Bs + rb * 64 + (((ss * 4 + lk) ^ (rb & 7)) * 8));
      }
#pragma unroll
      for (int i = 0; i < 4; ++i)
#pragma unroll
        for (int j = 0; j < 4; ++j)
          acc[i][j] = __builtin_amdgcn_mfma_f32_16x16x32_bf16(af[i], bv[j], acc[i][j], 0, 0, 0);
    }
  }

#pragma unroll
  for (int i = 0; i < 4; ++i) {
#pragma unroll
    for (int j = 0; j < 4; ++j) {
#pragma unroll
      for (int r2 = 0; r2 < 4; ++r2) {
        const int row = m0 + wr * 64 + i * 16 + lk * 4 + r2;
        const int col = n0 + wc * 64 + j * 16 + lrow;
        const float v = acc[i][j][r2];
        if constexpr (EPI == 0) {
          Cout[(size_t)kz * M * ldc + (size_t)row * ldc + col] = v;
        } else if constexpr (EPI == 1) {
          if (col < INNER) o0[(size_t)row * ldo + col] = __float2bfloat16(v);
          else             o1[(size_t)row * ldo + (col - INNER)] = __float2bfloat16(v);
        } else {
          o0[(size_t)kz * M * ldc + (size_t)row * ldc + col] = __float2bfloat16(v);
        }
      }
    }
  }
}

// ---------------------------------------------------------------- split-K4 reduce (bf16 partials -> fp32 out)
__global__ __launch_bounds__(256) void reduce4b_kernel(
    const __hip_bfloat16* __restrict__ P, float* __restrict__ out, int n4) {
  int i = blockIdx.x * 256 + threadIdx.x;
  if (i >= n4) return;
  float4 acc = make_float4(0.f, 0.f, 0.f, 0.f);
#pragma unroll
  for (int pp = 0; pp < 4; ++pp) {
    ushort4 u = ((const ushort4*)P)[(size_t)pp * n4 + i];
    acc.x += bf2f(u.x); acc.y += bf2f(u.y); acc.z += bf2f(u.z); acc.w += bf2f(u.w);
  }
  ((float4*)out)[i] = acc;
}

// ---------------------------------------------------------------- causal depthwise conv + silu
__global__ __launch_bounds__(256) void conv_silu_kernel(
    const __hip_bfloat16* __restrict__ xin, const float* __restrict__ cw,
    const float* __restrict__ cb, __hip_bfloat16* __restrict__ xch) {
  int idx = blockIdx.x * 256 + threadIdx.x;
  int cg = idx & 511;
  int tok = idx >> 9;
  int c = cg * 4;
  int l = tok & (SEQ - 1);
  float wv[4][4];
#pragma unroll
  for (int i = 0; i < 4; ++i) {
    float4 w = *(const float4*)&cw[(c + i) * 4];
    wv[i][0] = w.x; wv[i][1] = w.y; wv[i][2] = w.z; wv[i][3] = w.w;
  }
  float4 bias = *(const float4*)&cb[c];
  float r0 = bias.x, r1 = bias.y, r2 = bias.z, r3 = bias.w;
#pragma unroll
  for (int k = 0; k < 4; ++k) {
    const int d = 3 - k;
    if (l >= d) {
      ushort4 xv = *(const ushort4*)&xin[(size_t)(tok - d) * LDI + c];
      r0 = fmaf(bf2f(xv.x), wv[0][k], r0);
      r1 = fmaf(bf2f(xv.y), wv[1][k], r1);
      r2 = fmaf(bf2f(xv.z), wv[2][k], r2);
      r3 = fmaf(bf2f(xv.w), wv[3][k], r3);
    }
  }
  r0 = r0 / (1.f + __expf(-r0));
  r1 = r1 / (1.f + __expf(-r1));
  r2 = r2 / (1.f + __expf(-r2));
  r3 = r3 / (1.f + __expf(-r3));
  ushort4 u;
  u.x = f2bf(r0); u.y = f2bf(r1); u.z = f2bf(r2); u.w = f2bf(r3);
  *(ushort4*)&xch[(size_t)tok * LDI + c] = u;
}

// ---------------------------------------------------------------- scanprep: cumv (blocks 0..2047) + chunkG (2048..2303)
// cumv: LDS-staged P0+P1 -> softplus -> cumsum -> cumT/wT (coalesced uint4 stores).
// chunkG: P(B|C cols) -> tril(C@B^T) + C/B^T bf16 copies, t-quartered.
__global__ __launch_bounds__(256) void scanprep_kernel(
    const __hip_bfloat16* __restrict__ P, const float* __restrict__ bdt,
    const __hip_bfloat16* __restrict__ xch,
    unsigned short* __restrict__ cumT, unsigned int* __restrict__ wT,
    __hip_bfloat16* __restrict__ Abuf, __hip_bfloat16* __restrict__ BtBuf) {
  __shared__ __align__(16) char smem[34816];
  const unsigned short* P0 = (const unsigned short*)P;
  const unsigned short* P1 = P0 + (size_t)NTOK * NMID;

  if (blockIdx.x < 2048) {
    // ---------------- cumv ----------------
    float (*dpre)[68] = (float(*)[68])smem;
    float (*xcs)[68] = (float(*)[68])(smem + 64 * 68 * 4);
    const int bk = blockIdx.x >> 5;
    const int c0 = (blockIdx.x & 31) * 64;
    const int b = bk >> 5, k = bk & 31;
    const size_t tokbase = (size_t)(b * SEQ + k * TCHUNK);
    const unsigned short* XC = (const unsigned short*)xch;

    const int g = threadIdx.x & 15;
    const int r0 = threadIdx.x >> 4;
    const float4 bias4 = *(const float4*)&bdt[c0 + g * 4];
#pragma unroll
    for (int rr = 0; rr < 4; ++rr) {
      const int row = r0 + rr * 16;
      const size_t tok = tokbase + row;
      ushort4 u0 = *(const ushort4*)&P0[tok * NMID + c0 + g * 4];
      ushort4 u1 = *(const ushort4*)&P1[tok * NMID + c0 + g * 4];
      ushort4 ux = *(const ushort4*)&XC[tok * LDI + c0 + g * 4];
      float4 d = make_float4(bf2f(u0.x) + bf2f(u1.x) + bias4.x,
                             bf2f(u0.y) + bf2f(u1.y) + bias4.y,
                             bf2f(u0.z) + bf2f(u1.z) + bias4.z,
                             bf2f(u0.w) + bf2f(u1.w) + bias4.w);
      *(float4*)&dpre[row][g * 4] = d;
      *(float4*)&xcs[row][g * 4] = make_float4(bf2f(ux.x), bf2f(ux.y), bf2f(ux.z), bf2f(ux.w));
    }
    __syncthreads();

    const int cl = threadIdx.x >> 2, h = threadIdx.x & 3;
    const int c = c0 + cl;
    float dt[16], ls[16];
    float sdt = 0.f;
#pragma unroll
    for (int j = 0; j < 16; ++j) {
      const int t = h * 16 + j;
      const float dp = dpre[t][cl];
      const float dtv = (dp > 15.f) ? dp : log1pf(__expf(dp));
      dt[j] = dtv;
      sdt += dtv;
      ls[j] = sdt;
    }
    const int lane = threadIdx.x & 63;
    const int gbase = lane & ~3;
    const float s0 = __shfl(sdt, gbase + 0);
    const float s1 = __shfl(sdt, gbase + 1);
    const float s2 = __shfl(sdt, gbase + 2);
    float pre = 0.f;
    if (h > 0) pre += s0;
    if (h > 1) pre += s1;
    if (h > 2) pre += s2;
    unsigned int creg[8], wreg[8];
#pragma unroll
    for (int j = 0; j < 16; ++j) {
      const int t = h * 16 + j;
      const float st = fminf(pre + ls[j], 80.f);
      const float cg = __expf(-st);
      const float wi = __expf(st);
      const unsigned short cb = f2bf(cg);
      const unsigned short wb = f2bf(dt[j] * xcs[t][cl] * wi);
      if (j & 1) {
        creg[j >> 1] |= ((unsigned int)cb) << 16;
        wreg[j >> 1] |= ((unsigned int)wb) << 16;
      } else {
        creg[j >> 1] = (unsigned int)cb;
        wreg[j >> 1] = (unsigned int)wb;
      }
    }
    uint4* cd = (uint4*)((unsigned int*)cumT + ((size_t)bk * INNER + c) * 32 + h * 8);
    cd[0] = make_uint4(creg[0], creg[1], creg[2], creg[3]);
    cd[1] = make_uint4(creg[4], creg[5], creg[6], creg[7]);
    uint4* wd = (uint4*)(wT + ((size_t)bk * INNER + c) * 32 + h * 8);
    wd[0] = make_uint4(wreg[0], wreg[1], wreg[2], wreg[3]);
    wd[1] = make_uint4(wreg[4], wreg[5], wreg[6], wreg[7]);
  } else {
    // ---------------- chunkG ----------------
    float (*Bsh)[68] = (float(*)[68])smem;
    float (*Csh)[68] = (float(*)[68])(smem + 64 * 68 * 4);
    const int blk = blockIdx.x - 2048;
    const int bk = blk >> 2, qt = blk & 3;
    const int b = bk >> 5, k = bk & 31;
    const int tid = threadIdx.x;
    const size_t tokbase = (size_t)(b * SEQ + k * TCHUNK);

    for (int i = tid; i < TCHUNK * 16; i += 256) {
      const int row = i >> 4, q = i & 15;
      const size_t off = (tokbase + row) * NMID + INNER + q * 4;
      ushort4 u0 = *(const ushort4*)&P0[off];
      ushort4 u1 = *(const ushort4*)&P1[off];
      *(float4*)&Bsh[row][q * 4] = make_float4(
          bf2f(u0.x) + bf2f(u1.x), bf2f(u0.y) + bf2f(u1.y),
          bf2f(u0.z) + bf2f(u1.z), bf2f(u0.w) + bf2f(u1.w));
    }
    for (int i = tid; i < 16 * 16; i += 256) {
      const int row = i >> 4, q = i & 15;
      const size_t off = (tokbase + qt * 16 + row) * NMID + INNER + NSTATE + q * 4;
      ushort4 u0 = *(const ushort4*)&P0[off];
      ushort4 u1 = *(const ushort4*)&P1[off];
      *(float4*)&Csh[row][q * 4] = make_float4(
          bf2f(u0.x) + bf2f(u1.x), bf2f(u0.y) + bf2f(u1.y),
          bf2f(u0.z) + bf2f(u1.z), bf2f(u0.w) + bf2f(u1.w));
    }
    __syncthreads();
    for (int e = tid; e < 16 * 64; e += 256) {
      const int tl = e >> 6, tau = e & 63;
      const int t = qt * 16 + tl;
      float gg = 0.f;
      if (tau <= t) {
#pragma unroll
        for (int q = 0; q < 16; ++q) {
          const float4 cv = *(const float4*)&Csh[tl][q * 4];
          const float4 bv = *(const float4*)&Bsh[tau][q * 4];
          gg += cv.x * bv.x + cv.y * bv.y + cv.z * bv.z + cv.w * bv.w;
        }
      }
      Abuf[((size_t)bk * 64 + t) * 128 + tau] = __float2bfloat16(gg);
    }
    for (int e = tid; e < 16 * 64; e += 256) {
      const int n2l = e >> 6, r = e & 63;
      const int n2 = qt * 16 + n2l;
      BtBuf[((size_t)bk * 64 + n2) * 64 + r] = __float2bfloat16(Bsh[r][n2]);
      Abuf[((size_t)bk * 64 + n2) * 128 + 64 + r] = __float2bfloat16(Csh[n2l][r]);
    }
  }
}

// ---------------------------------------------------------------- S_loc GEMM: S[bk][c][n] (bf16) = cumT[c][63]*(wT@BtBuf^T)
__global__ __launch_bounds__(256, 4) void sloc_gemm_kernel(
    const __hip_bfloat16* __restrict__ wT, const __hip_bfloat16* __restrict__ BtBuf,
    const unsigned short* __restrict__ cumT, unsigned short* __restrict__ S) {
  __shared__ __align__(16) __hip_bfloat16 As[128 * 64];
  __shared__ __align__(16) __hip_bfloat16 Bs[64 * 64];
  const int tid = threadIdx.x;
  const int lane = tid & 63;
  const int w = tid >> 6;
  const int bk = blockIdx.x >> 4;
  const int ct = blockIdx.x & 15;
  const int c0 = ct * 128;

  const int g8row = lane >> 3;
  const int scol = ((lane & 7) ^ g8row) * 8;
  const __hip_bfloat16* Ag = wT + ((size_t)bk * INNER + c0 + w * 32 + g8row) * 64 + scol;
  const __hip_bfloat16* Bg = BtBuf + ((size_t)bk * 64 + w * 16 + g8row) * 64 + scol;
  __hip_bfloat16* lA = As + (w * 32) * 64;
  __hip_bfloat16* lB = Bs + (w * 16) * 64;
#pragma unroll
  for (int g = 0; g < 4; ++g) gload16(Ag + (size_t)(g * 8) * 64, lA + (g * 8) * 64);
#pragma unroll
  for (int g = 0; g < 2; ++g) gload16(Bg + (size_t)(g * 8) * 64, lB + (g * 8) * 64);
  __syncthreads();

  const int lrow = lane & 15, lk = lane >> 4;
  f32x4 acc[2][4];
#pragma unroll
  for (int i = 0; i < 2; ++i)
#pragma unroll
    for (int j = 0; j < 4; ++j)
#pragma unroll
      for (int r2 = 0; r2 < 4; ++r2) acc[i][j][r2] = 0.f;

#pragma unroll
  for (int ss = 0; ss < 2; ++ss) {
    bf16x8 af[2], bv[4];
#pragma unroll
    for (int i = 0; i < 2; ++i) {
      const int ra = w * 32 + i * 16 + lrow;
      af[i] = *(const bf16x8*)(As + ra * 64 + (((ss * 4 + lk) ^ (ra & 7)) * 8));
    }
#pragma unroll
    for (int j = 0; j < 4; ++j) {
      const int rb = j * 16 + lrow;
      bv[j] = *(const bf16x8*)(Bs + rb * 64 + (((ss * 4 + lk) ^ (rb & 7)) * 8));
    }
#pragma unroll
    for (int i = 0; i < 2; ++i)
#pragma unroll
      for (int j = 0; j < 4; ++j)
        acc[i][j] = __builtin_amdgcn_mfma_f32_16x16x32_bf16(af[i], bv[j], acc[i][j], 0, 0, 0);
  }

#pragma unroll
  for (int i = 0; i < 2; ++i) {
#pragma unroll
    for (int j = 0; j < 4; ++j) {
#pragma unroll
      for (int r2 = 0; r2 < 4; ++r2) {
        const int c = c0 + w * 32 + i * 16 + lk * 4 + r2;
        const int n = j * 16 + lrow;
        const float sc = bf2f(cumT[((size_t)bk * INNER + c) * 64 + 63]);
        S[((size_t)bk * INNER + c) * 64 + n] = f2bf(acc[i][j][r2] * sc);
      }
    }
  }
}

// ---------------------------------------------------------------- cross-chunk combine (in place, bf16 S)
__global__ __launch_bounds__(256) void scan_combine_kernel(
    unsigned short* __restrict__ S, const unsigned short* __restrict__ cumT) {
  const int idx = blockIdx.x * 256 + threadIdx.x;
  const int n = idx & 63;
  const int c = (idx >> 6) & (INNER - 1);
  const int b = idx >> 17;
  float s = 0.f;
  for (int k = 0; k < NCHUNK; ++k) {
    const size_t cs = (size_t)(b * NCHUNK + k) * INNER + c;
    const size_t off = cs * 64 + n;
    const float loc = bf2f(S[off]);
    S[off] = f2bf(s);
    const float ak = bf2f(cumT[cs * 64 + 63]);
    s = fmaf(ak, s, loc);
  }
}

// ---------------------------------------------------------------- y GEMM: [trilG|C] @ [wT;S_in] -> epilogue
__global__ __launch_bounds__(256, 4) void ypre_gemm_kernel(
    const __hip_bfloat16* __restrict__ Abuf, const __hip_bfloat16* __restrict__ wT,
    const unsigned short* __restrict__ S, const unsigned short* __restrict__ cumT,
    const __hip_bfloat16* __restrict__ xch, const __hip_bfloat16* __restrict__ zbf,
    const float* __restrict__ Dv, __hip_bfloat16* __restrict__ ygated) {
  __shared__ __align__(16) __hip_bfloat16 Asm[64 * 128];   // [t][k]
  __shared__ __align__(16) __hip_bfloat16 Bsm[128 * 128];  // [c][k]
  const int tid = threadIdx.x;
  const int lane = tid & 63;
  const int w = tid >> 6;
  const int bk = blockIdx.x >> 4;
  const int ct = blockIdx.x & 15;
  const int b = bk >> 5, k = bk & 31;
  const int c0 = ct * 128;

  {
#pragma unroll
    for (int g = 0; g < 4; ++g) {
      const int base = w * 16 + g * 4;
      const int col16s = (lane & 15) ^ ((base + (lane >> 4)) & 7);
      const __hip_bfloat16* src =
          Abuf + ((size_t)bk * 64 + base + (lane >> 4)) * 128 + col16s * 8;
      gload16(src, (char*)Asm + base * 256);
    }
  }
  {
    const int row = tid & 127, part = tid >> 7;
    const int c = c0 + row;
    if (part == 0) {
      const uint4* src = (const uint4*)(wT + ((size_t)bk * INNER + c) * 64);
#pragma unroll
      for (int s2 = 0; s2 < 8; ++s2) {
        uint4 v = src[s2];
        *(uint4*)((char*)Bsm + row * 256 + (s2 ^ (row & 7)) * 16) = v;
      }
    } else {
      const uint4* srcS = (const uint4*)(S + ((size_t)bk * INNER + c) * 64);
#pragma unroll
      for (int s2 = 0; s2 < 8; ++s2) {
        uint4 v = srcS[s2];
        *(uint4*)((char*)Bsm + row * 256 + ((8 + s2) ^ (row & 7)) * 16) = v;
      }
    }
  }
  __syncthreads();

  const int lrow = lane & 15, lk = lane >> 4;
  f32x4 acc[8];
#pragma unroll
  for (int j = 0; j < 8; ++j)
#pragma unroll
    for (int r2 = 0; r2 < 4; ++r2) acc[j][r2] = 0.f;

  const int ra = w * 16 + lrow;
#pragma unroll
  for (int kk = 0; kk < 4; ++kk) {
    const int csa = (kk * 4 + lk) ^ (ra & 7);
    bf16x8 af = *(const bf16x8*)((const char*)Asm + ra * 256 + csa * 16);
#pragma unroll
    for (int j = 0; j < 8; ++j) {
      const int rb = j * 16 + lrow;
      const int csb = (kk * 4 + lk) ^ (rb & 7);
      bf16x8 bv = *(const bf16x8*)((const char*)Bsm + rb * 256 + csb * 16);
      acc[j] = __builtin_amdgcn_mfma_f32_16x16x32_bf16(af, bv, acc[j], 0, 0, 0);
    }
  }

  const size_t tokb = (size_t)(b * SEQ + k * TCHUNK);
#pragma unroll
  for (int j = 0; j < 8; ++j) {
    const int c = c0 + j * 16 + lrow;
    const unsigned short* cp = cumT + ((size_t)bk * INNER + c) * 64 + w * 16 + lk * 4;
#pragma unroll
    for (int r2 = 0; r2 < 4; ++r2) {
      const int t = w * 16 + lk * 4 + r2;
      const size_t tok = tokb + t;
      const float ca = bf2f(cp[r2]);
      const float xc = bf2f(*(const unsigned short*)&xch[tok * LDI + c]);
      const float z = bf2f(*(const unsigned short*)&zbf[tok * LDI + c]);
      const float yt = ca * acc[j][r2] + Dv[c] * xc;
      const float g = z / (1.f + __expf(-z));
      *(unsigned short*)&ygated[tok * LDI + c] = f2bf(yt * g);
    }
  }
}

// ---------------------------------------------------------------- launch
extern "C" void kernel_launch(void* const* d_in, const int* in_sizes, int n_in,
                              void* d_out, int out_size, void* d_ws, size_t ws_size,
                              hipStream_t stream) {
  const float* x      = (const float*)d_in[0];
  const float* W_in   = (const float*)d_in[1];
  const float* conv_w = (const float*)d_in[2];
  const float* conv_b = (const float*)d_in[3];
  const float* W_dt   = (const float*)d_in[4];
  const float* b_dt   = (const float*)d_in[5];
  const float* W_B    = (const float*)d_in[6];
  const float* W_C    = (const float*)d_in[7];
  const float* Dvec   = (const float*)d_in[8];
  const float* W_out  = (const float*)d_in[9];
  float* out = (float*)d_out;

  char* p = (char*)d_ws;
  auto alloc = [&](size_t bytes) {
    char* r = p;
    p += (bytes + 255) & ~(size_t)255;
    return r;
  };
  __hip_bfloat16* xin   = (__hip_bfloat16*)alloc((size_t)NTOK * LDI * 2);  // later ygated
  __hip_bfloat16* zbf   = (__hip_bfloat16*)alloc((size_t)NTOK * LDI * 2);
  char*           scr   = alloc((size_t)NTOK * LDH * 2 + (size_t)2 * INNER * LDH * 2);
  __hip_bfloat16* WmidT = (__hip_bfloat16*)alloc((size_t)NMID * LDI * 2);
  __hip_bfloat16* WoutT = (__hip_bfloat16*)alloc((size_t)HID * LDI * 2);
  unsigned short* cumT  = (unsigned short*)alloc((size_t)BATCH * NCHUNK * INNER * TCHUNK * 2);
  __hip_bfloat16* wT    = (__hip_bfloat16*)alloc((size_t)BATCH * NCHUNK * INNER * TCHUNK * 2);
  __hip_bfloat16* Abuf  = (__hip_bfloat16*)alloc((size_t)BATCH * NCHUNK * 64 * 128 * 2);
  __hip_bfloat16* BtBuf = (__hip_bfloat16*)alloc((size_t)BATCH * NCHUNK * 64 * 64 * 2);
  __hip_bfloat16* Pmid  = (__hip_bfloat16*)alloc((size_t)2 * NTOK * NMID * 2);  // 35.7MB; later S / Pout

  __hip_bfloat16* x_bf   = (__hip_bfloat16*)scr;
  __hip_bfloat16* WinT   = (__hip_bfloat16*)(scr + (size_t)NTOK * LDH * 2);
  __hip_bfloat16* xch    = (__hip_bfloat16*)scr;
  __hip_bfloat16* ygated = xin;
  unsigned short* S      = (unsigned short*)Pmid;  // 16MB, after scanprep (last Pmid reader)
  __hip_bfloat16* Pout   = Pmid;                   // 33.5MB, after ypre

  // 1. prep: all weight transposes + x cvt (one launch)
  prep_kernel<<<NB_PREP, 256, 0, stream>>>(
      W_in, W_dt, W_B, W_C, W_out, x, WinT, WmidT, WoutT, x_bf);

  // 2. xz = x @ W_in -> split bf16 (xin | z)
  {
    const int gridN = (2 * INNER) / 128, nwg = (NTOK / 128) * gridN;
    gemm_bt_kernel<1><<<nwg, 256, 0, stream>>>(
        x_bf, WinT, NTOK, 2 * INNER, HID, LDH, gridN, nwg, nwg, nullptr, 0, LDI, xin, zbf);
  }

  // 3. conv + silu
  conv_silu_kernel<<<(NTOK * (INNER / 4)) / 256, 256, 0, stream>>>(xin, conv_w, conv_b, xch);

  // 4. mid GEMM split-K x2 (bf16 partials)
  {
    const int gridN = NMID / 128;
    const int mnwg = (NTOK / 128) * gridN;
    const int nwg = mnwg * 2;
    gemm_bt_kernel<2><<<nwg, 256, 0, stream>>>(
        xch, WmidT, NTOK, NMID, INNER / 2, LDI, gridN, nwg, mnwg, nullptr, NMID, 0,
        Pmid, nullptr);
  }

  // 5. scanprep (cumv + chunkG fused into one launch)
  scanprep_kernel<<<2304, 256, 0, stream>>>(
      Pmid, b_dt, xch, cumT, (unsigned int*)wT, Abuf, BtBuf);

  // 6. S_loc GEMM + cross-chunk combine + y GEMM
  sloc_gemm_kernel<<<BATCH * NCHUNK * 16, 256, 0, stream>>>(wT, BtBuf, cumT, S);
  scan_combine_kernel<<<(BATCH * INNER * NSTATE) / 256, 256, 0, stream>>>(S, cumT);
  ypre_gemm_kernel<<<BATCH * NCHUNK * 16, 256, 0, stream>>>(
      Abuf, wT, S, cumT, xch, zbf, Dvec, ygated);

  // 7. out = ygated @ W_out, split-K x4 (bf16 partials) + reduce
  {
    const int gridN = HID / 128;
    const int mnwg = (NTOK / 128) * gridN;
    const int nwg = mnwg * 4;
    gemm_bt_kernel<2><<<nwg, 256, 0, stream>>>(
        ygated, WoutT, NTOK, HID, INNER / 4, LDI, gridN, nwg, mnwg, nullptr, HID, 0,
        Pout, nullptr);
    const int n4 = NTOK * HID / 4;
    reduce4b_kernel<<<(n4 + 255) / 256, 256, 0, stream>>>(Pout, out, n4);
  }
}